// Round 4
// baseline (207.675 us; speedup 1.0000x reference)
//
#include <hip/hip_runtime.h>
#include <math.h>

#define B_    4
#define CH_   256
#define H_    48
#define W_    160
#define A_    36
#define K2_   9
#define HW_   (H_*W_)        // 7680
#define NPIX_ (B_*HW_)       // 30720
#define KTOT_ (CH_*K2_)      // 2304
#define CPC_  32             // channels per chunk
#define KC_   (CPC_*K2_)     // 288 k' per chunk
#define NCHK_ (CH_/CPC_)     // 8
#define NKST_ (KTOT_/32)     // 72 k-steps of 32
#define LSTR_ 296            // LDS row stride (ushort) for v11/v2 paths
#define PT2_  64             // pixel tile (col image granularity)
#define NBLK_ (NPIX_/PT2_)   // 480 col pixel-blocks
#define COLB_ 36864          // bytes per (block,chunk) col image: 36 granules*64px*16B
#define COLW_ (COLB_/2)      // 18432 ushorts
#define PT4_  32             // GEMM pixel tile (px-split)
#define NB4_  (NPIX_/PT4_)   // 960 GEMM blocks
#define HCW_  (COLW_/2)      // 9216 ushorts = 18432 B per (chunk, 32px half)

typedef __attribute__((ext_vector_type(8))) short bf16x8;
typedef __attribute__((ext_vector_type(4))) float f32x4;

__device__ inline ushort f2bf(float f) {
    union { float f; unsigned u; } c; c.f = f;
    unsigned r = c.u + 0x7FFFu + ((c.u >> 16) & 1u);
    return (ushort)(r >> 16);
}
__device__ inline float bf2f(ushort u) {
    union { unsigned u; float f; } c; c.u = (unsigned)u << 16; return c.f;
}

// async global->LDS, 16B per lane: LDS dest = wave-uniform base + lane*16
__device__ inline void gld_lds16(const ushort* g, ushort* l) {
    __builtin_amdgcn_global_load_lds(
        (const __attribute__((address_space(1))) unsigned int*)(g),
        (__attribute__((address_space(3))) unsigned int*)(l),
        16, 0, 0);
}

// counted vmcnt wait — n must fold to a literal (call from unrolled loop)
__device__ inline void vm_wait_n(int n) {
    if (n >= 4)      asm volatile("s_waitcnt vmcnt(4)" ::: "memory");
    else if (n == 2) asm volatile("s_waitcnt vmcnt(2)" ::: "memory");
    else             asm volatile("s_waitcnt vmcnt(0)" ::: "memory");
}

// ---------------- weight fp32 -> bf16, MFMA-fragment-ordered ----------------
__global__ __launch_bounds__(256)
void prep_weight2(const float* __restrict__ w, ushort* __restrict__ wp2) {
    int t = blockIdx.x * 256 + threadIdx.x;
    if (t >= CH_ * KTOT_) return;
    int j    = t & 7;
    int lane = (t >> 3) & 63;
    int kk   = t >> 9;             // 0..1151
    int kst  = kk % NKST_;
    int rg   = kk / NKST_;         // 0..15
    int row  = rg * 16 + (lane & 15);
    int kq   = kst * 32 + (lane >> 4) * 8 + j;   // k'
    int chunk = kq / KC_, r = kq % KC_;
    int tap = r / CPC_, ci = r % CPC_;
    int c = chunk * CPC_ + ci;
    wp2[t] = f2bf(w[(row * CH_ + c) * K2_ + tap]);
}

// ---------------- weight fp32 -> bf16, K-permuted (fallback layout) ----------
__global__ __launch_bounds__(256)
void prep_weight(const float* __restrict__ w, ushort* __restrict__ wp) {
    int t = blockIdx.x * 256 + threadIdx.x;
    if (t >= CH_ * KTOT_) return;
    int o  = t / KTOT_, kk = t % KTOT_;
    int chunk = kk / KC_, r = kk % KC_;
    int tap = r / CPC_, ci = r % CPC_;
    int c = chunk * CPC_ + ci;
    wp[t] = f2bf(w[(o * CH_ + c) * K2_ + tap]);
}

// ---------------- x [B,C,HW] f32 -> xt [B,HW,C] bf16 ----------------
__global__ __launch_bounds__(256)
void prep_xt(const float* __restrict__ x, ushort* __restrict__ xt) {
    int bid = blockIdx.x;
    int hwT = bid % (HW_ / 128);           // 60
    int rest = bid / (HW_ / 128);
    int cT = rest & 3;
    int b  = rest >> 2;
    int hw0 = hwT * 128, c0 = cT * 64;
    int tid = threadIdx.x;
    int u = tid & 7, s = tid >> 3;
    const float* xb = x + ((long)b * CH_ + c0 + u * 8) * HW_ + hw0 + s * 4;
    float4 L[8];
    #pragma unroll
    for (int i = 0; i < 8; ++i) L[i] = *(const float4*)(xb + (long)i * HW_);
    ushort* xo = xt + ((long)b * HW_ + hw0 + s * 4) * CH_ + c0 + u * 8;
    #pragma unroll
    for (int j = 0; j < 4; ++j) {
        bf16x8 o;
        #pragma unroll
        for (int i = 0; i < 8; ++i) {
            float f = (j == 0) ? L[i].x : (j == 1) ? L[i].y : (j == 2) ? L[i].z : L[i].w;
            o[i] = (short)f2bf(f);
        }
        *(bf16x8*)(xo + (long)j * CH_) = o;
    }
}

// ---------------- top-k gating + offset blend -> m, off (global) ----------
__global__ __launch_bounds__(256)
void gating_kernel(const float* __restrict__ prob,
                   const float* __restrict__ table,
                   float* __restrict__ m_out,
                   float* __restrict__ off_out) {
    int pix = blockIdx.x * 256 + threadIdx.x;
    if (pix >= NPIX_) return;
    int b  = pix / HW_;
    int hw = pix % HW_;
    const float* pr = prob + (long)b * A_ * HW_ + hw;

    float v0 = -1e30f, v1 = -1e30f, v2 = -1e30f;
    int   i0 = 0, i1 = 0, i2 = 0;
    #pragma unroll 4
    for (int a = 0; a < A_; ++a) {
        float v = pr[(long)a * HW_];
        if (v > v0)      { v2=v1; i2=i1; v1=v0; i1=i0; v0=v; i0=a; }
        else if (v > v1) { v2=v1; i2=i1; v1=v;  i1=a; }
        else if (v > v2) { v2=v;  i2=a; }
    }
    float e1 = expf(v1 - v0), e2 = expf(v2 - v0);
    float inv = 1.0f / (1.0f + e1 + e2);
    float s0 = inv, s1 = e1*inv, s2 = e2*inv;
    float hard = (v0 > 0.5f) ? 1.0f : 0.0f;

    m_out[pix] = v0;
    const float* t0 = table + ((long)i0 * 18) * HW_ + hw;
    const float* t1 = table + ((long)i1 * 18) * HW_ + hw;
    const float* t2 = table + ((long)i2 * 18) * HW_ + hw;
    float* op = off_out + (long)pix * 18;
    #pragma unroll
    for (int c = 0; c < 18; ++c) {
        float o = s0 * t0[(long)c * HW_] + s1 * t1[(long)c * HW_] + s2 * t2[(long)c * HW_];
        op[c] = o * hard;
    }
}

// ======== v14a: im2col, chunk-split — 3840 blocks, no LDS, no barriers ========
__global__ __launch_bounds__(576)
void im2col_k2(const ushort* __restrict__ xt,
               const float* __restrict__ m_arr,
               const float* __restrict__ off_arr,
               ushort* __restrict__ colg) {
    const int tid  = threadIdx.x;
    const int lane = tid & 63;
    const int wv   = tid >> 6;            // 0..8
    const int bid  = (int)blockIdx.x;
    const int chI  = bid & 7;             // chunk == XCD slot
    const int pbk  = bid >> 3;            // 0..479 pixel-block
    const int pb   = pbk * PT2_;
    const int b    = pb / HW_;
    const int hw0  = pb % HW_;
    const ushort* xtb = xt + (long)b * HW_ * CH_;
    ushort* cgo = colg + (long)pbk * (NCHK_ * COLW_) + (long)chI * COLW_;

    const int sseg = lane & 3;
    const int qd   = lane >> 2;
    const int cb0  = chI * CPC_ + sseg * 8;

    int   coff[4][4];
    float cwgt[4][4];
    int   gdst[4];
    #pragma unroll
    for (int g = 0; g < 4; ++g) {
        int pr = g * 144 + wv * 16 + qd;   // bijective over 0..575
        int px = pr & 63, kt = pr >> 6;
        int hw = hw0 + px;
        int pix = pb + px;
        int h  = hw / W_, w_ = hw % W_;
        float m    = m_arr[pix];
        float offh = off_arr[(long)pix * 18 + 2*kt];
        float offw = off_arr[(long)pix * 18 + 2*kt + 1];
        float py  = (float)(h  + (kt / 3 - 1)) + offh;
        float pxf = (float)(w_ + (kt % 3 - 1)) + offw;
        float y0f = floorf(py), x0f = floorf(pxf);
        float dy = py - y0f,   dx = pxf - x0f;
        int y0 = (int)y0f, x0i = (int)x0f;
        int y1 = y0 + 1,   x1  = x0i + 1;
        float vy0 = (y0  >= 0 && y0  < H_) ? 1.f : 0.f;
        float vy1 = (y1  >= 0 && y1  < H_) ? 1.f : 0.f;
        float vx0 = (x0i >= 0 && x0i < W_) ? 1.f : 0.f;
        float vx1 = (x1  >= 0 && x1  < W_) ? 1.f : 0.f;
        int cy0 = min(max(y0, 0),  H_-1), cy1 = min(max(y1, 0), H_-1);
        int cx0 = min(max(x0i, 0), W_-1), cx1 = min(max(x1, 0), W_-1);
        coff[g][0] = (cy0*W_ + cx0) * CH_;  cwgt[g][0] = (1.f-dy)*(1.f-dx)*vy0*vx0*m;
        coff[g][1] = (cy0*W_ + cx1) * CH_;  cwgt[g][1] = (1.f-dy)*dx      *vy0*vx1*m;
        coff[g][2] = (cy1*W_ + cx0) * CH_;  cwgt[g][2] = dy      *(1.f-dx)*vy1*vx0*m;
        coff[g][3] = (cy1*W_ + cx1) * CH_;  cwgt[g][3] = dy      *dx      *vy1*vx1*m;
        gdst[g] = ((kt * 4 + sseg) * 64 + px) * 8;
    }

    // 16 gathers issued back-to-back, then blend + 4 stores
    bf16x8 d[4][4];
    #pragma unroll
    for (int g = 0; g < 4; ++g)
        #pragma unroll
        for (int c = 0; c < 4; ++c)
            d[g][c] = *(const bf16x8*)(xtb + coff[g][c] + cb0);
    #pragma unroll
    for (int g = 0; g < 4; ++g) {
        float a8[8];
        #pragma unroll
        for (int j = 0; j < 8; ++j) a8[j] = 0.f;
        #pragma unroll
        for (int c = 0; c < 4; ++c) {
            float wgt = cwgt[g][c];
            #pragma unroll
            for (int j = 0; j < 8; ++j)
                a8[j] = fmaf(wgt, bf2f((ushort)d[g][c][j]), a8[j]);
        }
        bf16x8 o;
        #pragma unroll
        for (int j = 0; j < 8; ++j) o[j] = (short)f2bf(a8[j]);
        *(bf16x8*)(cgo + gdst[g]) = o;
    }
}

// ======== v15: GEMM with counted-vmcnt deep pipeline (T4) ========
// 4-buffer LDS ring (73.7 KB, 2 blocks/CU), prefetch depth 3. Per chunk:
// s_waitcnt vmcnt(4) waits ONLY the own oldest chunk's 2 loads — chunks
// chI+1, chI+2 stay in flight ACROSS the raw s_barrier (no __syncthreads
// vmcnt(0) drain, which was conv_gemm2's 94us disease). One barrier/chunk:
// stage(chI+3) reuses the buffer last read at chunk chI-1, certified done
// by this iteration's barrier.
__global__ __launch_bounds__(576)
void conv_gemm3(const float* __restrict__ x,
                const ushort* __restrict__ colg,
                const ushort* __restrict__ wp2,
                const float* __restrict__ bias,
                float* __restrict__ out) {
    __shared__ __align__(16) ushort colL[4][HCW_];   // 4 x 18432 B = 73728 B

    const int tid  = threadIdx.x;
    const int lane = tid & 63;
    const int wv   = tid >> 6;            // 0..8
    const int l15  = lane & 15;
    const int l16  = lane >> 4;
    const int bid  = (int)blockIdx.x;
    const int bswz = (bid & 7) * (NB4_ / 8) + (bid >> 3);   // 960 % 8 == 0
    const int cb64 = bswz >> 1;           // 64px col block
    const int half = bswz & 1;            // which 32px half
    const int pb   = bswz * PT4_;
    const int b    = pb / HW_;
    const int hw0  = pb % HW_;
    const long xb  = (long)b * CH_ * HW_;
    const ushort* cg = colg + (long)cb64 * (NCHK_ * COLW_) + half * 32 * 8;

    f32x4 acc[2][2];
    #pragma unroll
    for (int m = 0; m < 2; ++m)
        #pragma unroll
        for (int n = 0; n < 2; ++n)
            acc[m][n] = (f32x4)(0.f);

    const int rg0 = wv * 2;
    const int mg  = wv * 32;

    // stage one (chunk, 32px-half) image: 1152 16B units, 2 per thread
    auto STAGE = [&](int chI, int bufi) {
        const ushort* src = cg + (long)chI * COLW_;
        #pragma unroll
        for (int i = 0; i < 2; ++i) {
            const int u = (wv * 2 + i) * 64 + lane;
            const int g = u >> 5, p = u & 31;
            gld_lds16(src + (g * 64 + p) * 8,
                      (ushort*)colL[bufi] + (wv * 2 + i) * 512);
        }
    };
    auto COMPUTE = [&](int bufi, int chI) {
        if (wv < 8) {
            #pragma unroll
            for (int ks = 0; ks < K2_; ++ks) {
                const int kst = chI * K2_ + ks;
                const ushort* wr = wp2 + (((long)rg0 * NKST_ + kst) << 9) + (lane << 3);
                bf16x8 a0 = *(const bf16x8*)(wr);
                bf16x8 a1 = *(const bf16x8*)(wr + (1l * NKST_ << 9));
                const ushort* cb = &colL[bufi][((ks * 4 + l16) * 32 + l15) * 8];
                bf16x8 b0 = *(const bf16x8*)(cb);
                bf16x8 b1 = *(const bf16x8*)(cb + 16 * 8);
                __builtin_amdgcn_s_setprio(1);
                acc[0][0] = __builtin_amdgcn_mfma_f32_16x16x32_bf16(a0, b0, acc[0][0], 0, 0, 0);
                acc[0][1] = __builtin_amdgcn_mfma_f32_16x16x32_bf16(a0, b1, acc[0][1], 0, 0, 0);
                acc[1][0] = __builtin_amdgcn_mfma_f32_16x16x32_bf16(a1, b0, acc[1][0], 0, 0, 0);
                acc[1][1] = __builtin_amdgcn_mfma_f32_16x16x32_bf16(a1, b1, acc[1][1], 0, 0, 0);
                __builtin_amdgcn_s_setprio(0);
            }
        }
    };

    // prologue: 3 chunks in flight (6 loads/wave)
    STAGE(0, 0); STAGE(1, 1); STAGE(2, 2);

    #pragma unroll
    for (int chI = 0; chI < NCHK_; ++chI) {
        // outstanding chunks before wait: [chI .. min(chI+2,7)]
        const int nafter = 2 * ((NCHK_ - 1 < chI + 2 ? NCHK_ - 1 : chI + 2) - chI);
        vm_wait_n(nafter);                      // own chunk-chI loads landed
        __builtin_amdgcn_s_barrier();           // everyone's chI loads landed
        __builtin_amdgcn_sched_barrier(0);      // pin: nothing hoists above
        if (chI + 3 < NCHK_) STAGE(chI + 3, (chI + 3) & 3);  // stays in flight
        COMPUTE(chI & 3, chI);
    }

    if (wv < 8) {
        #pragma unroll
        for (int m = 0; m < 2; ++m)
            #pragma unroll
            for (int n = 0; n < 2; ++n)
                #pragma unroll
                for (int r = 0; r < 4; ++r) {
                    int o  = mg + m * 16 + l16 * 4 + r;
                    int hw = hw0 + n * 16 + l15;
                    long oi = xb + (long)o * HW_ + hw;
                    out[oi] = acc[m][n][r] + bias[o] + x[oi];
                }
    }
}

// ======== v11 (proven 140 us) — mid-tier if ws can't hold col ========
__global__ __launch_bounds__(576)
void conv_mfma11(const float* __restrict__ x,
                 const ushort* __restrict__ xt,
                 const ushort* __restrict__ wp2,
                 const float* __restrict__ prob,
                 const float* __restrict__ table,
                 const float* __restrict__ bias,
                 float* __restrict__ out) {
    __shared__ __align__(16) ushort col[2][PT2_ * LSTR_];   // 75776 B
    __shared__ float off_l[PT2_ * 18];
    __shared__ float m_l[PT2_];

    const int tid  = threadIdx.x;
    const int lane = tid & 63;
    const int wv   = tid >> 6;
    const int l15  = lane & 15;
    const int l16  = lane >> 4;
    const int bid  = (int)blockIdx.x;
    const int bswz = (bid & 7) * (NBLK_ / 8) + (bid >> 3);
    const int pb   = bswz * PT2_;
    const int b    = pb / HW_;
    const int hw0  = pb % HW_;
    const long xb  = (long)b * CH_ * HW_;
    const ushort* xtb = xt + (long)b * HW_ * CH_;

    if (tid < PT2_) {
        const int px = tid;
        const int hw = hw0 + px;
        const float* pr = prob + (long)b * A_ * HW_ + hw;
        float v0 = -1e30f, v1 = -1e30f, v2 = -1e30f;
        int   i0 = 0, i1 = 0, i2 = 0;
        #pragma unroll 4
        for (int a = 0; a < A_; ++a) {
            float v = pr[(long)a * HW_];
            if (v > v0)      { v2=v1; i2=i1; v1=v0; i1=i0; v0=v; i0=a; }
            else if (v > v1) { v2=v1; i2=i1; v1=v;  i1=a; }
            else if (v > v2) { v2=v;  i2=a; }
        }
        float e1 = expf(v1 - v0), e2 = expf(v2 - v0);
        float inv = 1.0f / (1.0f + e1 + e2);
        float s0 = inv, s1 = e1*inv, s2 = e2*inv;
        float hard = (v0 > 0.5f) ? 1.0f : 0.0f;
        m_l[px] = v0;
        const float* t0 = table + ((long)i0 * 18) * HW_ + hw;
        const float* t1 = table + ((long)i1 * 18) * HW_ + hw;
        const float* t2 = table + ((long)i2 * 18) * HW_ + hw;
        #pragma unroll
        for (int c = 0; c < 18; ++c) {
            float o = s0 * t0[(long)c * HW_] + s1 * t1[(long)c * HW_] + s2 * t2[(long)c * HW_];
            off_l[px * 18 + c] = o * hard;
        }
    }
    __syncthreads();

    const int sseg = lane & 3;
    const int qd   = lane >> 2;
    int   coff[4][4];
    float cwgt[4][4];
    int   dsto[4];
    #pragma unroll
    for (int g = 0; g < 4; ++g) {
        int pr = g * 144 + wv * 16 + qd;
        int px = pr & 63, kt = pr >> 6;
        int hw = hw0 + px;
        int h  = hw / W_, w_ = hw % W_;
        float m    = m_l[px];
        float offh = off_l[px * 18 + 2*kt];
        float offw = off_l[px * 18 + 2*kt + 1];
        float py  = (float)(h  + (kt / 3 - 1)) + offh;
        float pxf = (float)(w_ + (kt % 3 - 1)) + offw;
        float y0f = floorf(py), x0f = floorf(pxf);
        float dy = py - y0f,   dx = pxf - x0f;
        int y0 = (int)y0f, x0i = (int)x0f;
        int y1 = y0 + 1,   x1  = x0i + 1;
        float vy0 = (y0  >= 0 && y0  < H_) ? 1.f : 0.f;
        float vy1 = (y1  >= 0 && y1  < H_) ? 1.f : 0.f;
        float vx0 = (x0i >= 0 && x0i < W_) ? 1.f : 0.f;
        float vx1 = (x1  >= 0 && x1  < W_) ? 1.f : 0.f;
        int cy0 = min(max(y0, 0),  H_-1), cy1 = min(max(y1, 0), H_-1);
        int cx0 = min(max(x0i, 0), W_-1), cx1 = min(max(x1, 0), W_-1);
        coff[g][0] = (cy0*W_ + cx0) * CH_;  cwgt[g][0] = (1.f-dy)*(1.f-dx)*vy0*vx0*m;
        coff[g][1] = (cy0*W_ + cx1) * CH_;  cwgt[g][1] = (1.f-dy)*dx      *vy0*vx1*m;
        coff[g][2] = (cy1*W_ + cx0) * CH_;  cwgt[g][2] = dy      *(1.f-dx)*vy1*vx0*m;
        coff[g][3] = (cy1*W_ + cx1) * CH_;  cwgt[g][3] = dy      *dx      *vy1*vx1*m;
        dsto[g] = px * LSTR_ + kt * CPC_ + sseg * 8;
    }

    f32x4 acc[2][4];
    #pragma unroll
    for (int m = 0; m < 2; ++m)
        #pragma unroll
        for (int n = 0; n < 4; ++n)
            acc[m][n] = (f32x4)(0.f);

    const int rg0 = wv * 2;
    const int mg  = wv * 32;

    bf16x8 d[2][4];

    auto LOADpair = [&](int chI, int g0) {
        const int cb0 = chI * CPC_ + sseg * 8;
        #pragma unroll
        for (int gg = 0; gg < 2; ++gg)
            #pragma unroll
            for (int c = 0; c < 4; ++c)
                d[gg][c] = *(const bf16x8*)(xtb + coff[g0 + gg][c] + cb0);
    };
    auto WRITEpair = [&](int bufi, int g0) {
        #pragma unroll
        for (int gg = 0; gg < 2; ++gg) {
            float a8[8];
            #pragma unroll
            for (int j = 0; j < 8; ++j) a8[j] = 0.f;
            #pragma unroll
            for (int c = 0; c < 4; ++c) {
                float wgt = cwgt[g0 + gg][c];
                #pragma unroll
                for (int j = 0; j < 8; ++j)
                    a8[j] = fmaf(wgt, bf2f((ushort)d[gg][c][j]), a8[j]);
            }
            bf16x8 o;
            #pragma unroll
            for (int j = 0; j < 8; ++j) o[j] = (short)f2bf(a8[j]);
            *(bf16x8*)(&col[bufi][dsto[g0 + gg]]) = o;
        }
    };
    auto COMPUTEhalf = [&](int bufi, int chI, int ks0, int ks1) {
        if (wv < 8) {
            for (int ks = ks0; ks < ks1; ++ks) {
                const int kst = chI * K2_ + ks;
                const ushort* wr = wp2 + (((long)rg0 * NKST_ + kst) << 9) + (lane << 3);
                bf16x8 a0 = *(const bf16x8*)(wr);
                bf16x8 a1 = *(const bf16x8*)(wr + (1l * NKST_ << 9));
                const ushort* cb = &col[bufi][l15 * LSTR_ + ks * 32 + 8 * l16];
                bf16x8 b0 = *(const bf16x8*)(cb);
                bf16x8 b1 = *(const bf16x8*)(cb + 16 * LSTR_);
                bf16x8 b2 = *(const bf16x8*)(cb + 32 * LSTR_);
                bf16x8 b3 = *(const bf16x8*)(cb + 48 * LSTR_);
                __builtin_amdgcn_s_setprio(1);
                acc[0][0] = __builtin_amdgcn_mfma_f32_16x16x32_bf16(a0, b0, acc[0][0], 0, 0, 0);
                acc[0][1] = __builtin_amdgcn_mfma_f32_16x16x32_bf16(a0, b1, acc[0][1], 0, 0, 0);
                acc[0][2] = __builtin_amdgcn_mfma_f32_16x16x32_bf16(a0, b2, acc[0][2], 0, 0, 0);
                acc[0][3] = __builtin_amdgcn_mfma_f32_16x16x32_bf16(a0, b3, acc[0][3], 0, 0, 0);
                acc[1][0] = __builtin_amdgcn_mfma_f32_16x16x32_bf16(a1, b0, acc[1][0], 0, 0, 0);
                acc[1][1] = __builtin_amdgcn_mfma_f32_16x16x32_bf16(a1, b1, acc[1][1], 0, 0, 0);
                acc[1][2] = __builtin_amdgcn_mfma_f32_16x16x32_bf16(a1, b2, acc[1][2], 0, 0, 0);
                acc[1][3] = __builtin_amdgcn_mfma_f32_16x16x32_bf16(a1, b3, acc[1][3], 0, 0, 0);
                __builtin_amdgcn_s_setprio(0);
            }
        }
    };

    LOADpair(0, 0); WRITEpair(0, 0);
    LOADpair(0, 2); WRITEpair(0, 2);
    __syncthreads();

    for (int chI = 0; chI < NCHK_; ++chI) {
        const int cur = chI & 1, nxt = cur ^ 1;
        const bool pf = (chI < NCHK_ - 1);
        if (pf) LOADpair(chI + 1, 0);
        COMPUTEhalf(cur, chI, 0, 4);
        if (pf) { WRITEpair(nxt, 0); LOADpair(chI + 1, 2); }
        COMPUTEhalf(cur, chI, 4, 9);
        if (pf) WRITEpair(nxt, 2);
        __syncthreads();
    }

    if (wv < 8) {
        #pragma unroll
        for (int m = 0; m < 2; ++m)
            #pragma unroll
            for (int n = 0; n < 4; ++n)
                #pragma unroll
                for (int r = 0; r < 4; ++r) {
                    int o  = mg + m * 16 + l16 * 4 + r;
                    int hw = hw0 + n * 16 + l15;
                    long oi = xb + (long)o * HW_ + hw;
                    out[oi] = acc[m][n][r] + bias[o] + x[oi];
                }
    }
}

// ======== v2 fallback (used if ws too small) ========
__global__ __launch_bounds__(576)
void conv_mfma2(const float* __restrict__ x,
                const ushort* __restrict__ wp,
                const float* __restrict__ bias,
                const float* __restrict__ m_arr,
                const float* __restrict__ off_arr,
                float* __restrict__ out) {
    __shared__ __align__(16) ushort col[PT2_ * LSTR_];

    const int tid  = threadIdx.x;
    const int lane = tid & 63;
    const int wv   = tid >> 6;
    const int l15  = lane & 15;
    const int l16  = lane >> 4;
    const int pb   = blockIdx.x * PT2_;
    const int b    = pb / HW_;
    const int hw0  = pb % HW_;
    const long xb  = (long)b * CH_ * HW_;

    int   id0, id1, id2, id3;
    float wg0, wg1, wg2, wg3;
    {
        int px = lane, kt = wv;
        int hw = hw0 + px;
        int h  = hw / W_, w_ = hw % W_;
        int pix = b * HW_ + hw;
        float m    = m_arr[pix];
        float offh = off_arr[(long)pix * 18 + 2*kt];
        float offw = off_arr[(long)pix * 18 + 2*kt + 1];
        float py = (float)(h  + (kt / 3 - 1)) + offh;
        float px_= (float)(w_ + (kt % 3 - 1)) + offw;
        float y0f = floorf(py), x0f = floorf(px_);
        float dy = py - y0f,   dx = px_ - x0f;
        int y0 = (int)y0f, x0 = (int)x0f;
        int y1 = y0 + 1,   x1 = x0 + 1;
        float vy0 = (y0 >= 0 && y0 < H_) ? 1.f : 0.f;
        float vy1 = (y1 >= 0 && y1 < H_) ? 1.f : 0.f;
        float vx0 = (x0 >= 0 && x0 < W_) ? 1.f : 0.f;
        float vx1 = (x1 >= 0 && x1 < W_) ? 1.f : 0.f;
        int cy0 = min(max(y0, 0), H_-1), cy1 = min(max(y1, 0), H_-1);
        int cx0 = min(max(x0, 0), W_-1), cx1 = min(max(x1, 0), W_-1);
        id0 = cy0*W_ + cx0;  wg0 = (1.f-dy)*(1.f-dx)*vy0*vx0*m;
        id1 = cy0*W_ + cx1;  wg1 = (1.f-dy)*dx      *vy0*vx1*m;
        id2 = cy1*W_ + cx0;  wg2 = dy      *(1.f-dx)*vy1*vx0*m;
        id3 = cy1*W_ + cx1;  wg3 = dy      *dx      *vy1*vx1*m;
    }

    f32x4 acc[4][2];
    #pragma unroll
    for (int m = 0; m < 4; ++m)
        #pragma unroll
        for (int n = 0; n < 2; ++n)
            acc[m][n] = (f32x4)(0.f);

    const int mg = (wv & 3) * 64;
    const int pg = (wv >> 2) * 32;

    for (int chI = 0; chI < NCHK_; ++chI) {
        __syncthreads();
        {
            const int c0 = chI * CPC_;
            ushort* dst = &col[lane * LSTR_ + wv * CPC_];
            #pragma unroll
            for (int c8 = 0; c8 < 4; ++c8) {
                bf16x8 pk;
                #pragma unroll
                for (int j = 0; j < 8; ++j) {
                    const float* xs = x + xb + (long)(c0 + c8*8 + j) * HW_;
                    float v = wg0 * xs[id0] + wg1 * xs[id1]
                            + wg2 * xs[id2] + wg3 * xs[id3];
                    pk[j] = (short)f2bf(v);
                }
                *(bf16x8*)(dst + c8 * 8) = pk;
            }
        }
        __syncthreads();
        if (wv < 8) {
            #pragma unroll
            for (int ks = 0; ks < K2_; ++ks) {
                const int kg = chI * KC_ + ks * 32 + 8 * l16;
                const ushort* wr = wp + (long)(mg + l15) * KTOT_ + kg;
                bf16x8 a0 = *(const bf16x8*)(wr);
                bf16x8 a1 = *(const bf16x8*)(wr + 16 * KTOT_);
                bf16x8 a2 = *(const bf16x8*)(wr + 32 * KTOT_);
                bf16x8 a3 = *(const bf16x8*)(wr + 48 * KTOT_);
                const ushort* cb = &col[(pg + l15) * LSTR_ + ks * 32 + 8 * l16];
                bf16x8 b0 = *(const bf16x8*)(cb);
                bf16x8 b1 = *(const bf16x8*)(cb + 16 * LSTR_);
                acc[0][0] = __builtin_amdgcn_mfma_f32_16x16x32_bf16(a0, b0, acc[0][0], 0, 0, 0);
                acc[0][1] = __builtin_amdgcn_mfma_f32_16x16x32_bf16(a0, b1, acc[0][1], 0, 0, 0);
                acc[1][0] = __builtin_amdgcn_mfma_f32_16x16x32_bf16(a1, b0, acc[1][0], 0, 0, 0);
                acc[1][1] = __builtin_amdgcn_mfma_f32_16x16x32_bf16(a1, b1, acc[1][1], 0, 0, 0);
                acc[2][0] = __builtin_amdgcn_mfma_f32_16x16x32_bf16(a2, b0, acc[2][0], 0, 0, 0);
                acc[2][1] = __builtin_amdgcn_mfma_f32_16x16x32_bf16(a2, b1, acc[2][1], 0, 0, 0);
                acc[3][0] = __builtin_amdgcn_mfma_f32_16x16x32_bf16(a3, b0, acc[3][0], 0, 0, 0);
                acc[3][1] = __builtin_amdgcn_mfma_f32_16x16x32_bf16(a3, b1, acc[3][1], 0, 0, 0);
            }
        }
    }

    if (wv < 8) {
        #pragma unroll
        for (int m = 0; m < 4; ++m)
            #pragma unroll
            for (int n = 0; n < 2; ++n)
                #pragma unroll
                for (int r = 0; r < 4; ++r) {
                    int o  = mg + m * 16 + l16 * 4 + r;
                    int hw = hw0 + pg + n * 16 + l15;
                    long oi = xb + (long)o * HW_ + hw;
                    out[oi] = acc[m][n][r] + bias[o] + x[oi];
                }
    }
}

extern "C" void kernel_launch(void* const* d_in, const int* in_sizes, int n_in,
                              void* d_out, int out_size, void* d_ws, size_t ws_size,
                              hipStream_t stream) {
    const float* x      = (const float*)d_in[0];
    const float* prob   = (const float*)d_in[1];
    const float* table  = (const float*)d_in[2];
    const float* weight = (const float*)d_in[3];
    const float* bias   = (const float*)d_in[4];
    float* out = (float*)d_out;

    const size_t wp_bytes  = (size_t)CH_ * KTOT_ * 2;          // 1,179,648
    const size_t m_bytes   = (size_t)NPIX_ * 4;                // 122,880
    const size_t off_bytes = (size_t)NPIX_ * 18 * 4;           // 2,211,840
    const size_t xt_bytes  = (size_t)NPIX_ * CH_ * 2;          // 15,728,640
    const size_t col_bytes = (size_t)NBLK_ * NCHK_ * COLB_;    // 141,557,760

    ushort* wp_ws  = (ushort*)d_ws;
    float*  m_ws   = (float*)((char*)d_ws + wp_bytes);
    float*  off_ws = (float*)((char*)d_ws + wp_bytes + m_bytes);
    ushort* xt_ws  = (ushort*)((char*)d_ws + wp_bytes + m_bytes + off_bytes);
    ushort* col_ws = (ushort*)((char*)d_ws + wp_bytes + m_bytes + off_bytes + xt_bytes);

    const size_t need_v11 = wp_bytes + m_bytes + off_bytes + xt_bytes;
    const size_t need_v15 = need_v11 + col_bytes;

    if (ws_size >= need_v15) {
        prep_weight2<<<(CH_ * KTOT_ + 255) / 256, 256, 0, stream>>>(weight, wp_ws);
        prep_xt<<<(HW_ / 128) * 4 * B_, 256, 0, stream>>>(x, xt_ws);
        gating_kernel<<<NPIX_ / 256, 256, 0, stream>>>(prob, table, m_ws, off_ws);
        im2col_k2<<<NBLK_ * NCHK_, 576, 0, stream>>>(xt_ws, m_ws, off_ws, col_ws);
        conv_gemm3<<<NB4_, 576, 0, stream>>>(x, col_ws, wp_ws, bias, out);
    } else if (ws_size >= need_v11) {
        prep_weight2<<<(CH_ * KTOT_ + 255) / 256, 256, 0, stream>>>(weight, wp_ws);
        prep_xt<<<(HW_ / 128) * 4 * B_, 256, 0, stream>>>(x, xt_ws);
        conv_mfma11<<<NBLK_, 576, 0, stream>>>(x, xt_ws, wp_ws, prob, table, bias, out);
    } else {
        gating_kernel<<<NPIX_ / 256, 256, 0, stream>>>(prob, table, m_ws, off_ws);
        prep_weight<<<(CH_ * KTOT_ + 255) / 256, 256, 0, stream>>>(weight, wp_ws);
        conv_mfma2<<<NPIX_ / PT2_, 576, 0, stream>>>(x, wp_ws, bias, m_ws, off_ws, out);
    }
}

// Round 5
// 195.228 us; speedup vs baseline: 1.0638x; 1.0638x over previous
//
#include <hip/hip_runtime.h>
#include <math.h>

#define B_    4
#define CH_   256
#define H_    48
#define W_    160
#define A_    36
#define K2_   9
#define HW_   (H_*W_)        // 7680
#define NPIX_ (B_*HW_)       // 30720
#define KTOT_ (CH_*K2_)      // 2304
#define CPC_  32             // channels per chunk
#define KC_   (CPC_*K2_)     // 288 k' per chunk
#define NCHK_ (CH_/CPC_)     // 8
#define NKST_ (KTOT_/32)     // 72 k-steps of 32
#define LSTR_ 296            // LDS row stride (ushort) for v11/v2 paths
#define PT2_  64             // pixel tile (col image granularity + GEMM tile)
#define NBLK_ (NPIX_/PT2_)   // 480 blocks
#define COLB_ 36864          // bytes per (block,chunk) col image: 36 granules*64px*16B
#define COLW_ (COLB_/2)      // 18432 ushorts

typedef __attribute__((ext_vector_type(8))) short bf16x8;
typedef __attribute__((ext_vector_type(4))) float f32x4;

__device__ inline ushort f2bf(float f) {
    union { float f; unsigned u; } c; c.f = f;
    unsigned r = c.u + 0x7FFFu + ((c.u >> 16) & 1u);
    return (ushort)(r >> 16);
}
__device__ inline float bf2f(ushort u) {
    union { unsigned u; float f; } c; c.u = (unsigned)u << 16; return c.f;
}

// async global->LDS, 16B per lane: LDS dest = wave-uniform base + lane*16
__device__ inline void gld_lds16(const ushort* g, ushort* l) {
    __builtin_amdgcn_global_load_lds(
        (const __attribute__((address_space(1))) unsigned int*)(g),
        (__attribute__((address_space(3))) unsigned int*)(l),
        16, 0, 0);
}

// ---------------- weight fp32 -> bf16, MFMA-fragment-ordered ----------------
__global__ __launch_bounds__(256)
void prep_weight2(const float* __restrict__ w, ushort* __restrict__ wp2) {
    int t = blockIdx.x * 256 + threadIdx.x;
    if (t >= CH_ * KTOT_) return;
    int j    = t & 7;
    int lane = (t >> 3) & 63;
    int kk   = t >> 9;             // 0..1151
    int kst  = kk % NKST_;
    int rg   = kk / NKST_;         // 0..15
    int row  = rg * 16 + (lane & 15);
    int kq   = kst * 32 + (lane >> 4) * 8 + j;   // k'
    int chunk = kq / KC_, r = kq % KC_;
    int tap = r / CPC_, ci = r % CPC_;
    int c = chunk * CPC_ + ci;
    wp2[t] = f2bf(w[(row * CH_ + c) * K2_ + tap]);
}

// ---------------- weight fp32 -> bf16, K-permuted (fallback layout) ----------
__global__ __launch_bounds__(256)
void prep_weight(const float* __restrict__ w, ushort* __restrict__ wp) {
    int t = blockIdx.x * 256 + threadIdx.x;
    if (t >= CH_ * KTOT_) return;
    int o  = t / KTOT_, kk = t % KTOT_;
    int chunk = kk / KC_, r = kk % KC_;
    int tap = r / CPC_, ci = r % CPC_;
    int c = chunk * CPC_ + ci;
    wp[t] = f2bf(w[(o * CH_ + c) * K2_ + tap]);
}

// ---------------- x [B,C,HW] f32 -> xt [B,HW,C] bf16 ----------------
__global__ __launch_bounds__(256)
void prep_xt(const float* __restrict__ x, ushort* __restrict__ xt) {
    int bid = blockIdx.x;
    int hwT = bid % (HW_ / 128);           // 60
    int rest = bid / (HW_ / 128);
    int cT = rest & 3;
    int b  = rest >> 2;
    int hw0 = hwT * 128, c0 = cT * 64;
    int tid = threadIdx.x;
    int u = tid & 7, s = tid >> 3;
    const float* xb = x + ((long)b * CH_ + c0 + u * 8) * HW_ + hw0 + s * 4;
    float4 L[8];
    #pragma unroll
    for (int i = 0; i < 8; ++i) L[i] = *(const float4*)(xb + (long)i * HW_);
    ushort* xo = xt + ((long)b * HW_ + hw0 + s * 4) * CH_ + c0 + u * 8;
    #pragma unroll
    for (int j = 0; j < 4; ++j) {
        bf16x8 o;
        #pragma unroll
        for (int i = 0; i < 8; ++i) {
            float f = (j == 0) ? L[i].x : (j == 1) ? L[i].y : (j == 2) ? L[i].z : L[i].w;
            o[i] = (short)f2bf(f);
        }
        *(bf16x8*)(xo + (long)j * CH_) = o;
    }
}

// ---------------- top-k gating + offset blend -> m, off (global) ----------
__global__ __launch_bounds__(256)
void gating_kernel(const float* __restrict__ prob,
                   const float* __restrict__ table,
                   float* __restrict__ m_out,
                   float* __restrict__ off_out) {
    int pix = blockIdx.x * 256 + threadIdx.x;
    if (pix >= NPIX_) return;
    int b  = pix / HW_;
    int hw = pix % HW_;
    const float* pr = prob + (long)b * A_ * HW_ + hw;

    float v0 = -1e30f, v1 = -1e30f, v2 = -1e30f;
    int   i0 = 0, i1 = 0, i2 = 0;
    #pragma unroll 4
    for (int a = 0; a < A_; ++a) {
        float v = pr[(long)a * HW_];
        if (v > v0)      { v2=v1; i2=i1; v1=v0; i1=i0; v0=v; i0=a; }
        else if (v > v1) { v2=v1; i2=i1; v1=v;  i1=a; }
        else if (v > v2) { v2=v;  i2=a; }
    }
    float e1 = expf(v1 - v0), e2 = expf(v2 - v0);
    float inv = 1.0f / (1.0f + e1 + e2);
    float s0 = inv, s1 = e1*inv, s2 = e2*inv;
    float hard = (v0 > 0.5f) ? 1.0f : 0.0f;

    m_out[pix] = v0;
    const float* t0 = table + ((long)i0 * 18) * HW_ + hw;
    const float* t1 = table + ((long)i1 * 18) * HW_ + hw;
    const float* t2 = table + ((long)i2 * 18) * HW_ + hw;
    float* op = off_out + (long)pix * 18;
    #pragma unroll
    for (int c = 0; c < 18; ++c) {
        float o = s0 * t0[(long)c * HW_] + s1 * t1[(long)c * HW_] + s2 * t2[(long)c * HW_];
        op[c] = o * hard;
    }
}

// ======== v16a: im2col with store-coalesced mapping ========
// unit (g in 0..3, wv in 0..8) -> granule G = g*9 + wv, pixel = lane.
// A wave's 64 stores are ONE contiguous 1KB line (was: 16B scattered 1KB
// apart -> transaction-bound). kt = G>>2, sseg = G&3 (channel segment is
// wave-uniform per unit). Chunk-split (chI = bid&7 = XCD slot) kept: each
// XCD gathers only its own 1.97MB xt channel slice (L2-resident).
__global__ __launch_bounds__(576)
void im2col_k3(const ushort* __restrict__ xt,
               const float* __restrict__ m_arr,
               const float* __restrict__ off_arr,
               ushort* __restrict__ colg) {
    const int tid  = threadIdx.x;
    const int lane = tid & 63;
    const int wv   = tid >> 6;            // 0..8
    const int bid  = (int)blockIdx.x;
    const int chI  = bid & 7;             // chunk == XCD slot
    const int pbk  = bid >> 3;            // 0..479 pixel-block
    const int pb   = pbk * PT2_;
    const int b    = pb / HW_;
    const int hw0  = pb % HW_;
    const ushort* xtb = xt + (long)b * HW_ * CH_;
    ushort* cgo = colg + (long)pbk * (NCHK_ * COLW_) + (long)chI * COLW_;

    const int px  = lane;
    const int pix = pb + px;
    const int hw  = hw0 + px;
    const int h   = hw / W_, w_ = hw % W_;
    const float m = m_arr[pix];

    int   coff[4][4];
    float cwgt[4][4];
    int   gdst[4];
    #pragma unroll
    for (int g = 0; g < 4; ++g) {
        const int G    = g * 9 + wv;       // granule 0..35
        const int kt   = G >> 2;
        const int sseg = G & 3;
        const int cb0  = chI * CPC_ + sseg * 8;
        float2 ohw = *(const float2*)(off_arr + (long)pix * 18 + 2 * kt);
        float py  = (float)(h  + (kt / 3 - 1)) + ohw.x;
        float pxf = (float)(w_ + (kt % 3 - 1)) + ohw.y;
        float y0f = floorf(py), x0f = floorf(pxf);
        float dy = py - y0f,   dx = pxf - x0f;
        int y0 = (int)y0f, x0i = (int)x0f;
        int y1 = y0 + 1,   x1  = x0i + 1;
        float vy0 = (y0  >= 0 && y0  < H_) ? 1.f : 0.f;
        float vy1 = (y1  >= 0 && y1  < H_) ? 1.f : 0.f;
        float vx0 = (x0i >= 0 && x0i < W_) ? 1.f : 0.f;
        float vx1 = (x1  >= 0 && x1  < W_) ? 1.f : 0.f;
        int cy0 = min(max(y0, 0),  H_-1), cy1 = min(max(y1, 0), H_-1);
        int cx0 = min(max(x0i, 0), W_-1), cx1 = min(max(x1, 0), W_-1);
        coff[g][0] = (cy0*W_ + cx0) * CH_ + cb0;  cwgt[g][0] = (1.f-dy)*(1.f-dx)*vy0*vx0*m;
        coff[g][1] = (cy0*W_ + cx1) * CH_ + cb0;  cwgt[g][1] = (1.f-dy)*dx      *vy0*vx1*m;
        coff[g][2] = (cy1*W_ + cx0) * CH_ + cb0;  cwgt[g][2] = dy      *(1.f-dx)*vy1*vx0*m;
        coff[g][3] = (cy1*W_ + cx1) * CH_ + cb0;  cwgt[g][3] = dy      *dx      *vy1*vx1*m;
        gdst[g] = (G * 64 + px) * 8;       // wave-contiguous 1KB store
    }

    // 16 gathers issued back-to-back, then blend + 4 coalesced stores
    bf16x8 d[4][4];
    #pragma unroll
    for (int g = 0; g < 4; ++g)
        #pragma unroll
        for (int c = 0; c < 4; ++c)
            d[g][c] = *(const bf16x8*)(xtb + coff[g][c]);
    #pragma unroll
    for (int g = 0; g < 4; ++g) {
        float a8[8];
        #pragma unroll
        for (int j = 0; j < 8; ++j) a8[j] = 0.f;
        #pragma unroll
        for (int c = 0; c < 4; ++c) {
            float wgt = cwgt[g][c];
            #pragma unroll
            for (int j = 0; j < 8; ++j)
                a8[j] = fmaf(wgt, bf2f((ushort)d[g][c][j]), a8[j]);
        }
        bf16x8 o;
        #pragma unroll
        for (int j = 0; j < 8; ++j) o[j] = (short)f2bf(a8[j]);
        *(bf16x8*)(cgo + gdst[g]) = o;
    }
}

// ======== v16b: PT=64 GEMM (round-2 structure) + weight reg-pipeline ========
// 480 blocks x 9 waves. dbuf col LDS 2x36.9KB = 73.7KB (2 blocks/CU).
// STAGE: 4 gld_lds dwordx4 per thread (linear copy). COMPUTE: per ks the
// NEXT ks's weight fragments are loaded into registers while the current
// 8 MFMAs run — hides the ~200cyc L2 weight latency that dominated gemm2/3
// (their VGPR=36/44 showed the compiler never hoisted). Simple 2-phase
// __syncthreads: stage issued BEFORE compute, so its latency hides under
// ~700cyc of MFMA; the barrier drain then lands on completed loads.
__global__ __launch_bounds__(576)
void conv_gemm4(const float* __restrict__ x,
                const ushort* __restrict__ colg,
                const ushort* __restrict__ wp2,
                const float* __restrict__ bias,
                float* __restrict__ out) {
    __shared__ __align__(16) ushort colL[2][COLW_];   // 73728 B

    const int tid  = threadIdx.x;
    const int lane = tid & 63;
    const int wv   = tid >> 6;            // 0..8
    const int l15  = lane & 15;
    const int l16  = lane >> 4;
    const int bid  = (int)blockIdx.x;
    const int bswz = (bid & 7) * (NBLK_ / 8) + (bid >> 3);   // 480 % 8 == 0
    const int pb   = bswz * PT2_;
    const int b    = pb / HW_;
    const int hw0  = pb % HW_;
    const long xb  = (long)b * CH_ * HW_;
    const ushort* cg = colg + (long)bswz * (NCHK_ * COLW_);

    f32x4 acc[2][4];
    #pragma unroll
    for (int m = 0; m < 2; ++m)
        #pragma unroll
        for (int n = 0; n < 4; ++n)
            acc[m][n] = (f32x4)(0.f);

    const int rg0 = wv * 2;
    const int mg  = wv * 32;

    auto STAGE = [&](int chI, int bufi) {
        const ushort* src = cg + (long)chI * COLW_;
        #pragma unroll
        for (int i = 0; i < 4; ++i) {
            const int go = (wv * 4 + i) * 512;          // granule pair (ushorts)
            gld_lds16(src + go + lane * 8, (ushort*)colL[bufi] + go);
        }
    };
    auto COMPUTE = [&](int bufi, int chI) {
        if (wv < 8) {
            // wbase(ks) = fragment for (row-group rg0, kst = chI*9+ks)
            const ushort* wbase = wp2 + (((long)rg0 * NKST_ + chI * K2_) << 9) + (lane << 3);
            const long rstep = (long)NKST_ << 9;        // +1 row-group
            bf16x8 a0 = *(const bf16x8*)(wbase);
            bf16x8 a1 = *(const bf16x8*)(wbase + rstep);
            #pragma unroll
            for (int ks = 0; ks < K2_; ++ks) {
                bf16x8 a0n, a1n;
                if (ks < K2_ - 1) {                     // prefetch next ks
                    a0n = *(const bf16x8*)(wbase + ((ks + 1) << 9));
                    a1n = *(const bf16x8*)(wbase + rstep + ((ks + 1) << 9));
                }
                const ushort* cb = &colL[bufi][((ks * 4 + l16) * 64 + l15) * 8];
                bf16x8 b0 = *(const bf16x8*)(cb);
                bf16x8 b1 = *(const bf16x8*)(cb + 16 * 8);
                bf16x8 b2 = *(const bf16x8*)(cb + 32 * 8);
                bf16x8 b3 = *(const bf16x8*)(cb + 48 * 8);
                __builtin_amdgcn_s_setprio(1);
                acc[0][0] = __builtin_amdgcn_mfma_f32_16x16x32_bf16(a0, b0, acc[0][0], 0, 0, 0);
                acc[0][1] = __builtin_amdgcn_mfma_f32_16x16x32_bf16(a0, b1, acc[0][1], 0, 0, 0);
                acc[0][2] = __builtin_amdgcn_mfma_f32_16x16x32_bf16(a0, b2, acc[0][2], 0, 0, 0);
                acc[0][3] = __builtin_amdgcn_mfma_f32_16x16x32_bf16(a0, b3, acc[0][3], 0, 0, 0);
                acc[1][0] = __builtin_amdgcn_mfma_f32_16x16x32_bf16(a1, b0, acc[1][0], 0, 0, 0);
                acc[1][1] = __builtin_amdgcn_mfma_f32_16x16x32_bf16(a1, b1, acc[1][1], 0, 0, 0);
                acc[1][2] = __builtin_amdgcn_mfma_f32_16x16x32_bf16(a1, b2, acc[1][2], 0, 0, 0);
                acc[1][3] = __builtin_amdgcn_mfma_f32_16x16x32_bf16(a1, b3, acc[1][3], 0, 0, 0);
                __builtin_amdgcn_s_setprio(0);
                if (ks < K2_ - 1) { a0 = a0n; a1 = a1n; }
            }
        }
    };

    STAGE(0, 0);
    __syncthreads();                       // buf0 ready
    for (int chI = 0; chI < NCHK_; ++chI) {
        const int cur = chI & 1, nxt = cur ^ 1;
        if (chI < NCHK_ - 1) STAGE(chI + 1, nxt);   // latency hides under MFMA
        COMPUTE(cur, chI);
        __syncthreads();
    }

    if (wv < 8) {
        #pragma unroll
        for (int m = 0; m < 2; ++m)
            #pragma unroll
            for (int n = 0; n < 4; ++n)
                #pragma unroll
                for (int r = 0; r < 4; ++r) {
                    int o  = mg + m * 16 + l16 * 4 + r;
                    int hw = hw0 + n * 16 + l15;
                    long oi = xb + (long)o * HW_ + hw;
                    out[oi] = acc[m][n][r] + bias[o] + x[oi];
                }
    }
}

// ======== v11 (proven 140 us) — mid-tier if ws can't hold col ========
__global__ __launch_bounds__(576)
void conv_mfma11(const float* __restrict__ x,
                 const ushort* __restrict__ xt,
                 const ushort* __restrict__ wp2,
                 const float* __restrict__ prob,
                 const float* __restrict__ table,
                 const float* __restrict__ bias,
                 float* __restrict__ out) {
    __shared__ __align__(16) ushort col[2][PT2_ * LSTR_];   // 75776 B
    __shared__ float off_l[PT2_ * 18];
    __shared__ float m_l[PT2_];

    const int tid  = threadIdx.x;
    const int lane = tid & 63;
    const int wv   = tid >> 6;
    const int l15  = lane & 15;
    const int l16  = lane >> 4;
    const int bid  = (int)blockIdx.x;
    const int bswz = (bid & 7) * (NBLK_ / 8) + (bid >> 3);
    const int pb   = bswz * PT2_;
    const int b    = pb / HW_;
    const int hw0  = pb % HW_;
    const long xb  = (long)b * CH_ * HW_;
    const ushort* xtb = xt + (long)b * HW_ * CH_;

    if (tid < PT2_) {
        const int px = tid;
        const int hw = hw0 + px;
        const float* pr = prob + (long)b * A_ * HW_ + hw;
        float v0 = -1e30f, v1 = -1e30f, v2 = -1e30f;
        int   i0 = 0, i1 = 0, i2 = 0;
        #pragma unroll 4
        for (int a = 0; a < A_; ++a) {
            float v = pr[(long)a * HW_];
            if (v > v0)      { v2=v1; i2=i1; v1=v0; i1=i0; v0=v; i0=a; }
            else if (v > v1) { v2=v1; i2=i1; v1=v;  i1=a; }
            else if (v > v2) { v2=v;  i2=a; }
        }
        float e1 = expf(v1 - v0), e2 = expf(v2 - v0);
        float inv = 1.0f / (1.0f + e1 + e2);
        float s0 = inv, s1 = e1*inv, s2 = e2*inv;
        float hard = (v0 > 0.5f) ? 1.0f : 0.0f;
        m_l[px] = v0;
        const float* t0 = table + ((long)i0 * 18) * HW_ + hw;
        const float* t1 = table + ((long)i1 * 18) * HW_ + hw;
        const float* t2 = table + ((long)i2 * 18) * HW_ + hw;
        #pragma unroll
        for (int c = 0; c < 18; ++c) {
            float o = s0 * t0[(long)c * HW_] + s1 * t1[(long)c * HW_] + s2 * t2[(long)c * HW_];
            off_l[px * 18 + c] = o * hard;
        }
    }
    __syncthreads();

    const int sseg = lane & 3;
    const int qd   = lane >> 2;
    int   coff[4][4];
    float cwgt[4][4];
    int   dsto[4];
    #pragma unroll
    for (int g = 0; g < 4; ++g) {
        int pr = g * 144 + wv * 16 + qd;
        int px = pr & 63, kt = pr >> 6;
        int hw = hw0 + px;
        int h  = hw / W_, w_ = hw % W_;
        float m    = m_l[px];
        float offh = off_l[px * 18 + 2*kt];
        float offw = off_l[px * 18 + 2*kt + 1];
        float py  = (float)(h  + (kt / 3 - 1)) + offh;
        float pxf = (float)(w_ + (kt % 3 - 1)) + offw;
        float y0f = floorf(py), x0f = floorf(pxf);
        float dy = py - y0f,   dx = pxf - x0f;
        int y0 = (int)y0f, x0i = (int)x0f;
        int y1 = y0 + 1,   x1  = x0i + 1;
        float vy0 = (y0  >= 0 && y0  < H_) ? 1.f : 0.f;
        float vy1 = (y1  >= 0 && y1  < H_) ? 1.f : 0.f;
        float vx0 = (x0i >= 0 && x0i < W_) ? 1.f : 0.f;
        float vx1 = (x1  >= 0 && x1  < W_) ? 1.f : 0.f;
        int cy0 = min(max(y0, 0),  H_-1), cy1 = min(max(y1, 0), H_-1);
        int cx0 = min(max(x0i, 0), W_-1), cx1 = min(max(x1, 0), W_-1);
        coff[g][0] = (cy0*W_ + cx0) * CH_;  cwgt[g][0] = (1.f-dy)*(1.f-dx)*vy0*vx0*m;
        coff[g][1] = (cy0*W_ + cx1) * CH_;  cwgt[g][1] = (1.f-dy)*dx      *vy0*vx1*m;
        coff[g][2] = (cy1*W_ + cx0) * CH_;  cwgt[g][2] = dy      *(1.f-dx)*vy1*vx0*m;
        coff[g][3] = (cy1*W_ + cx1) * CH_;  cwgt[g][3] = dy      *dx      *vy1*vx1*m;
        dsto[g] = px * LSTR_ + kt * CPC_ + sseg * 8;
    }

    f32x4 acc[2][4];
    #pragma unroll
    for (int m = 0; m < 2; ++m)
        #pragma unroll
        for (int n = 0; n < 4; ++n)
            acc[m][n] = (f32x4)(0.f);

    const int rg0 = wv * 2;
    const int mg  = wv * 32;

    bf16x8 d[2][4];

    auto LOADpair = [&](int chI, int g0) {
        const int cb0 = chI * CPC_ + sseg * 8;
        #pragma unroll
        for (int gg = 0; gg < 2; ++gg)
            #pragma unroll
            for (int c = 0; c < 4; ++c)
                d[gg][c] = *(const bf16x8*)(xtb + coff[g0 + gg][c] + cb0);
    };
    auto WRITEpair = [&](int bufi, int g0) {
        #pragma unroll
        for (int gg = 0; gg < 2; ++gg) {
            float a8[8];
            #pragma unroll
            for (int j = 0; j < 8; ++j) a8[j] = 0.f;
            #pragma unroll
            for (int c = 0; c < 4; ++c) {
                float wgt = cwgt[g0 + gg][c];
                #pragma unroll
                for (int j = 0; j < 8; ++j)
                    a8[j] = fmaf(wgt, bf2f((ushort)d[gg][c][j]), a8[j]);
            }
            bf16x8 o;
            #pragma unroll
            for (int j = 0; j < 8; ++j) o[j] = (short)f2bf(a8[j]);
            *(bf16x8*)(&col[bufi][dsto[g0 + gg]]) = o;
        }
    };
    auto COMPUTEhalf = [&](int bufi, int chI, int ks0, int ks1) {
        if (wv < 8) {
            for (int ks = ks0; ks < ks1; ++ks) {
                const int kst = chI * K2_ + ks;
                const ushort* wr = wp2 + (((long)rg0 * NKST_ + kst) << 9) + (lane << 3);
                bf16x8 a0 = *(const bf16x8*)(wr);
                bf16x8 a1 = *(const bf16x8*)(wr + (1l * NKST_ << 9));
                const ushort* cb = &col[bufi][l15 * LSTR_ + ks * 32 + 8 * l16];
                bf16x8 b0 = *(const bf16x8*)(cb);
                bf16x8 b1 = *(const bf16x8*)(cb + 16 * LSTR_);
                bf16x8 b2 = *(const bf16x8*)(cb + 32 * LSTR_);
                bf16x8 b3 = *(const bf16x8*)(cb + 48 * LSTR_);
                __builtin_amdgcn_s_setprio(1);
                acc[0][0] = __builtin_amdgcn_mfma_f32_16x16x32_bf16(a0, b0, acc[0][0], 0, 0, 0);
                acc[0][1] = __builtin_amdgcn_mfma_f32_16x16x32_bf16(a0, b1, acc[0][1], 0, 0, 0);
                acc[0][2] = __builtin_amdgcn_mfma_f32_16x16x32_bf16(a0, b2, acc[0][2], 0, 0, 0);
                acc[0][3] = __builtin_amdgcn_mfma_f32_16x16x32_bf16(a0, b3, acc[0][3], 0, 0, 0);
                acc[1][0] = __builtin_amdgcn_mfma_f32_16x16x32_bf16(a1, b0, acc[1][0], 0, 0, 0);
                acc[1][1] = __builtin_amdgcn_mfma_f32_16x16x32_bf16(a1, b1, acc[1][1], 0, 0, 0);
                acc[1][2] = __builtin_amdgcn_mfma_f32_16x16x32_bf16(a1, b2, acc[1][2], 0, 0, 0);
                acc[1][3] = __builtin_amdgcn_mfma_f32_16x16x32_bf16(a1, b3, acc[1][3], 0, 0, 0);
                __builtin_amdgcn_s_setprio(0);
            }
        }
    };

    LOADpair(0, 0); WRITEpair(0, 0);
    LOADpair(0, 2); WRITEpair(0, 2);
    __syncthreads();

    for (int chI = 0; chI < NCHK_; ++chI) {
        const int cur = chI & 1, nxt = cur ^ 1;
        const bool pf = (chI < NCHK_ - 1);
        if (pf) LOADpair(chI + 1, 0);
        COMPUTEhalf(cur, chI, 0, 4);
        if (pf) { WRITEpair(nxt, 0); LOADpair(chI + 1, 2); }
        COMPUTEhalf(cur, chI, 4, 9);
        if (pf) WRITEpair(nxt, 2);
        __syncthreads();
    }

    if (wv < 8) {
        #pragma unroll
        for (int m = 0; m < 2; ++m)
            #pragma unroll
            for (int n = 0; n < 4; ++n)
                #pragma unroll
                for (int r = 0; r < 4; ++r) {
                    int o  = mg + m * 16 + l16 * 4 + r;
                    int hw = hw0 + n * 16 + l15;
                    long oi = xb + (long)o * HW_ + hw;
                    out[oi] = acc[m][n][r] + bias[o] + x[oi];
                }
    }
}

// ======== v2 fallback (used if ws too small) ========
__global__ __launch_bounds__(576)
void conv_mfma2(const float* __restrict__ x,
                const ushort* __restrict__ wp,
                const float* __restrict__ bias,
                const float* __restrict__ m_arr,
                const float* __restrict__ off_arr,
                float* __restrict__ out) {
    __shared__ __align__(16) ushort col[PT2_ * LSTR_];

    const int tid  = threadIdx.x;
    const int lane = tid & 63;
    const int wv   = tid >> 6;
    const int l15  = lane & 15;
    const int l16  = lane >> 4;
    const int pb   = blockIdx.x * PT2_;
    const int b    = pb / HW_;
    const int hw0  = pb % HW_;
    const long xb  = (long)b * CH_ * HW_;

    int   id0, id1, id2, id3;
    float wg0, wg1, wg2, wg3;
    {
        int px = lane, kt = wv;
        int hw = hw0 + px;
        int h  = hw / W_, w_ = hw % W_;
        int pix = b * HW_ + hw;
        float m    = m_arr[pix];
        float offh = off_arr[(long)pix * 18 + 2*kt];
        float offw = off_arr[(long)pix * 18 + 2*kt + 1];
        float py = (float)(h  + (kt / 3 - 1)) + offh;
        float px_= (float)(w_ + (kt % 3 - 1)) + offw;
        float y0f = floorf(py), x0f = floorf(px_);
        float dy = py - y0f,   dx = px_ - x0f;
        int y0 = (int)y0f, x0 = (int)x0f;
        int y1 = y0 + 1,   x1 = x0 + 1;
        float vy0 = (y0 >= 0 && y0 < H_) ? 1.f : 0.f;
        float vy1 = (y1 >= 0 && y1 < H_) ? 1.f : 0.f;
        float vx0 = (x0 >= 0 && x0 < W_) ? 1.f : 0.f;
        float vx1 = (x1 >= 0 && x1 < W_) ? 1.f : 0.f;
        int cy0 = min(max(y0, 0), H_-1), cy1 = min(max(y1, 0), H_-1);
        int cx0 = min(max(x0, 0), W_-1), cx1 = min(max(x1, 0), W_-1);
        id0 = cy0*W_ + cx0;  wg0 = (1.f-dy)*(1.f-dx)*vy0*vx0*m;
        id1 = cy0*W_ + cx1;  wg1 = (1.f-dy)*dx      *vy0*vx1*m;
        id2 = cy1*W_ + cx0;  wg2 = dy      *(1.f-dx)*vy1*vx0*m;
        id3 = cy1*W_ + cx1;  wg3 = dy      *dx      *vy1*vx1*m;
    }

    f32x4 acc[4][2];
    #pragma unroll
    for (int m = 0; m < 4; ++m)
        #pragma unroll
        for (int n = 0; n < 2; ++n)
            acc[m][n] = (f32x4)(0.f);

    const int mg = (wv & 3) * 64;
    const int pg = (wv >> 2) * 32;

    for (int chI = 0; chI < NCHK_; ++chI) {
        __syncthreads();
        {
            const int c0 = chI * CPC_;
            ushort* dst = &col[lane * LSTR_ + wv * CPC_];
            #pragma unroll
            for (int c8 = 0; c8 < 4; ++c8) {
                bf16x8 pk;
                #pragma unroll
                for (int j = 0; j < 8; ++j) {
                    const float* xs = x + xb + (long)(c0 + c8*8 + j) * HW_;
                    float v = wg0 * xs[id0] + wg1 * xs[id1]
                            + wg2 * xs[id2] + wg3 * xs[id3];
                    pk[j] = (short)f2bf(v);
                }
                *(bf16x8*)(dst + c8 * 8) = pk;
            }
        }
        __syncthreads();
        if (wv < 8) {
            #pragma unroll
            for (int ks = 0; ks < K2_; ++ks) {
                const int kg = chI * KC_ + ks * 32 + 8 * l16;
                const ushort* wr = wp + (long)(mg + l15) * KTOT_ + kg;
                bf16x8 a0 = *(const bf16x8*)(wr);
                bf16x8 a1 = *(const bf16x8*)(wr + 16 * KTOT_);
                bf16x8 a2 = *(const bf16x8*)(wr + 32 * KTOT_);
                bf16x8 a3 = *(const bf16x8*)(wr + 48 * KTOT_);
                const ushort* cb = &col[(pg + l15) * LSTR_ + ks * 32 + 8 * l16];
                bf16x8 b0 = *(const bf16x8*)(cb);
                bf16x8 b1 = *(const bf16x8*)(cb + 16 * LSTR_);
                acc[0][0] = __builtin_amdgcn_mfma_f32_16x16x32_bf16(a0, b0, acc[0][0], 0, 0, 0);
                acc[0][1] = __builtin_amdgcn_mfma_f32_16x16x32_bf16(a0, b1, acc[0][1], 0, 0, 0);
                acc[1][0] = __builtin_amdgcn_mfma_f32_16x16x32_bf16(a1, b0, acc[1][0], 0, 0, 0);
                acc[1][1] = __builtin_amdgcn_mfma_f32_16x16x32_bf16(a1, b1, acc[1][1], 0, 0, 0);
                acc[2][0] = __builtin_amdgcn_mfma_f32_16x16x32_bf16(a2, b0, acc[2][0], 0, 0, 0);
                acc[2][1] = __builtin_amdgcn_mfma_f32_16x16x32_bf16(a2, b1, acc[2][1], 0, 0, 0);
                acc[3][0] = __builtin_amdgcn_mfma_f32_16x16x32_bf16(a3, b0, acc[3][0], 0, 0, 0);
                acc[3][1] = __builtin_amdgcn_mfma_f32_16x16x32_bf16(a3, b1, acc[3][1], 0, 0, 0);
            }
        }
    }

    if (wv < 8) {
        #pragma unroll
        for (int m = 0; m < 4; ++m)
            #pragma unroll
            for (int n = 0; n < 2; ++n)
                #pragma unroll
                for (int r = 0; r < 4; ++r) {
                    int o  = mg + m * 16 + l16 * 4 + r;
                    int hw = hw0 + pg + n * 16 + l15;
                    long oi = xb + (long)o * HW_ + hw;
                    out[oi] = acc[m][n][r] + bias[o] + x[oi];
                }
    }
}

extern "C" void kernel_launch(void* const* d_in, const int* in_sizes, int n_in,
                              void* d_out, int out_size, void* d_ws, size_t ws_size,
                              hipStream_t stream) {
    const float* x      = (const float*)d_in[0];
    const float* prob   = (const float*)d_in[1];
    const float* table  = (const float*)d_in[2];
    const float* weight = (const float*)d_in[3];
    const float* bias   = (const float*)d_in[4];
    float* out = (float*)d_out;

    const size_t wp_bytes  = (size_t)CH_ * KTOT_ * 2;          // 1,179,648
    const size_t m_bytes   = (size_t)NPIX_ * 4;                // 122,880
    const size_t off_bytes = (size_t)NPIX_ * 18 * 4;           // 2,211,840
    const size_t xt_bytes  = (size_t)NPIX_ * CH_ * 2;          // 15,728,640
    const size_t col_bytes = (size_t)NBLK_ * NCHK_ * COLB_;    // 141,557,760

    ushort* wp_ws  = (ushort*)d_ws;
    float*  m_ws   = (float*)((char*)d_ws + wp_bytes);
    float*  off_ws = (float*)((char*)d_ws + wp_bytes + m_bytes);
    ushort* xt_ws  = (ushort*)((char*)d_ws + wp_bytes + m_bytes + off_bytes);
    ushort* col_ws = (ushort*)((char*)d_ws + wp_bytes + m_bytes + off_bytes + xt_bytes);

    const size_t need_v11 = wp_bytes + m_bytes + off_bytes + xt_bytes;
    const size_t need_v16 = need_v11 + col_bytes;

    if (ws_size >= need_v16) {
        prep_weight2<<<(CH_ * KTOT_ + 255) / 256, 256, 0, stream>>>(weight, wp_ws);
        prep_xt<<<(HW_ / 128) * 4 * B_, 256, 0, stream>>>(x, xt_ws);
        gating_kernel<<<NPIX_ / 256, 256, 0, stream>>>(prob, table, m_ws, off_ws);
        im2col_k3<<<NBLK_ * NCHK_, 576, 0, stream>>>(xt_ws, m_ws, off_ws, col_ws);
        conv_gemm4<<<NBLK_, 576, 0, stream>>>(x, col_ws, wp_ws, bias, out);
    } else if (ws_size >= need_v11) {
        prep_weight2<<<(CH_ * KTOT_ + 255) / 256, 256, 0, stream>>>(weight, wp_ws);
        prep_xt<<<(HW_ / 128) * 4 * B_, 256, 0, stream>>>(x, xt_ws);
        conv_mfma11<<<NBLK_, 576, 0, stream>>>(x, xt_ws, wp_ws, prob, table, bias, out);
    } else {
        gating_kernel<<<NPIX_ / 256, 256, 0, stream>>>(prob, table, m_ws, off_ws);
        prep_weight<<<(CH_ * KTOT_ + 255) / 256, 256, 0, stream>>>(weight, wp_ws);
        conv_mfma2<<<NPIX_ / PT2_, 576, 0, stream>>>(x, wp_ws, bias, m_ws, off_ws, out);
    }
}

// Round 6
// 135.841 us; speedup vs baseline: 1.5288x; 1.4372x over previous
//
#include <hip/hip_runtime.h>
#include <math.h>

#define B_    4
#define CH_   256
#define H_    48
#define W_    160
#define A_    36
#define K2_   9
#define HW_   (H_*W_)        // 7680
#define NPIX_ (B_*HW_)       // 30720
#define KTOT_ (CH_*K2_)      // 2304
#define CPC_  32             // channels per chunk
#define KC_   (CPC_*K2_)     // 288 k' per chunk
#define NCHK_ (CH_/CPC_)     // 8
#define NKST_ (KTOT_/32)     // 72 k-steps of 32
#define LSTR_ 296            // LDS row stride (ushort) for v11/v2 paths
#define PT2_  64             // pixel tile (col image granularity)
#define NBLK_ (NPIX_/PT2_)   // 480 col pixel-blocks
#define COLB_ 36864          // bytes per (64px-block,chunk) col image: 36 gran*64px*16B
#define COLW_ (COLB_/2)      // 18432 ushorts
#define PT5_  128            // GEMM pixel tile
#define NB5_  (NPIX_/PT5_)   // 240 GEMM blocks
#define TSTR_ 520            // im2col LDS granule stride (ushorts) = 1040B (pad)

typedef __attribute__((ext_vector_type(8))) short bf16x8;
typedef __attribute__((ext_vector_type(4))) float f32x4;

__device__ inline ushort f2bf(float f) {
    union { float f; unsigned u; } c; c.f = f;
    unsigned r = c.u + 0x7FFFu + ((c.u >> 16) & 1u);
    return (ushort)(r >> 16);
}
__device__ inline float bf2f(ushort u) {
    union { unsigned u; float f; } c; c.u = (unsigned)u << 16; return c.f;
}

// async global->LDS, 16B per lane: LDS dest = wave-uniform base + lane*16
__device__ inline void gld_lds16(const ushort* g, ushort* l) {
    __builtin_amdgcn_global_load_lds(
        (const __attribute__((address_space(1))) unsigned int*)(g),
        (__attribute__((address_space(3))) unsigned int*)(l),
        16, 0, 0);
}

// ---------------- weight fp32 -> bf16, MFMA-fragment-ordered ----------------
__global__ __launch_bounds__(256)
void prep_weight2(const float* __restrict__ w, ushort* __restrict__ wp2) {
    int t = blockIdx.x * 256 + threadIdx.x;
    if (t >= CH_ * KTOT_) return;
    int j    = t & 7;
    int lane = (t >> 3) & 63;
    int kk   = t >> 9;             // 0..1151
    int kst  = kk % NKST_;
    int rg   = kk / NKST_;         // 0..15
    int row  = rg * 16 + (lane & 15);
    int kq   = kst * 32 + (lane >> 4) * 8 + j;   // k'
    int chunk = kq / KC_, r = kq % KC_;
    int tap = r / CPC_, ci = r % CPC_;
    int c = chunk * CPC_ + ci;
    wp2[t] = f2bf(w[(row * CH_ + c) * K2_ + tap]);
}

// ---------------- weight fp32 -> bf16, K-permuted (fallback layout) ----------
__global__ __launch_bounds__(256)
void prep_weight(const float* __restrict__ w, ushort* __restrict__ wp) {
    int t = blockIdx.x * 256 + threadIdx.x;
    if (t >= CH_ * KTOT_) return;
    int o  = t / KTOT_, kk = t % KTOT_;
    int chunk = kk / KC_, r = kk % KC_;
    int tap = r / CPC_, ci = r % CPC_;
    int c = chunk * CPC_ + ci;
    wp[t] = f2bf(w[(o * CH_ + c) * K2_ + tap]);
}

// ---------------- x [B,C,HW] f32 -> xt [B,HW,C] bf16 ----------------
__global__ __launch_bounds__(256)
void prep_xt(const float* __restrict__ x, ushort* __restrict__ xt) {
    int bid = blockIdx.x;
    int hwT = bid % (HW_ / 128);           // 60
    int rest = bid / (HW_ / 128);
    int cT = rest & 3;
    int b  = rest >> 2;
    int hw0 = hwT * 128, c0 = cT * 64;
    int tid = threadIdx.x;
    int u = tid & 7, s = tid >> 3;
    const float* xb = x + ((long)b * CH_ + c0 + u * 8) * HW_ + hw0 + s * 4;
    float4 L[8];
    #pragma unroll
    for (int i = 0; i < 8; ++i) L[i] = *(const float4*)(xb + (long)i * HW_);
    ushort* xo = xt + ((long)b * HW_ + hw0 + s * 4) * CH_ + c0 + u * 8;
    #pragma unroll
    for (int j = 0; j < 4; ++j) {
        bf16x8 o;
        #pragma unroll
        for (int i = 0; i < 8; ++i) {
            float f = (j == 0) ? L[i].x : (j == 1) ? L[i].y : (j == 2) ? L[i].z : L[i].w;
            o[i] = (short)f2bf(f);
        }
        *(bf16x8*)(xo + (long)j * CH_) = o;
    }
}

// ---------------- top-k gating + offset blend -> m, off (global) ----------
__global__ __launch_bounds__(256)
void gating_kernel(const float* __restrict__ prob,
                   const float* __restrict__ table,
                   float* __restrict__ m_out,
                   float* __restrict__ off_out) {
    int pix = blockIdx.x * 256 + threadIdx.x;
    if (pix >= NPIX_) return;
    int b  = pix / HW_;
    int hw = pix % HW_;
    const float* pr = prob + (long)b * A_ * HW_ + hw;

    float v0 = -1e30f, v1 = -1e30f, v2 = -1e30f;
    int   i0 = 0, i1 = 0, i2 = 0;
    #pragma unroll 4
    for (int a = 0; a < A_; ++a) {
        float v = pr[(long)a * HW_];
        if (v > v0)      { v2=v1; i2=i1; v1=v0; i1=i0; v0=v; i0=a; }
        else if (v > v1) { v2=v1; i2=i1; v1=v;  i1=a; }
        else if (v > v2) { v2=v;  i2=a; }
    }
    float e1 = expf(v1 - v0), e2 = expf(v2 - v0);
    float inv = 1.0f / (1.0f + e1 + e2);
    float s0 = inv, s1 = e1*inv, s2 = e2*inv;
    float hard = (v0 > 0.5f) ? 1.0f : 0.0f;

    m_out[pix] = v0;
    const float* t0 = table + ((long)i0 * 18) * HW_ + hw;
    const float* t1 = table + ((long)i1 * 18) * HW_ + hw;
    const float* t2 = table + ((long)i2 * 18) * HW_ + hw;
    float* op = off_out + (long)pix * 18;
    #pragma unroll
    for (int c = 0; c < 18; ++c) {
        float o = s0 * t0[(long)c * HW_] + s1 * t1[(long)c * HW_] + s2 * t2[(long)c * HW_];
        op[c] = o * hard;
    }
}

// ======== v17a: im2col — coalesced gathers AND coalesced stores ========
// Phase 1 (k2's proven gather): unit (px,kt) per 4-lane cluster, sseg=lane&3
// -> each cluster reads contiguous 64B of one xt row (16 line-req/wave).
// Blend -> LDS transpose buffer [36 granules][64px][16B], granule stride
// padded to 1040B so the 4 ssegs of a cluster land in different bank groups.
// Phase 2: barrier, re-read granule-major (linear b128) and store: lane=px
// -> each wave writes ONE contiguous 1KB line (was 64 scattered 16B).
// Chunk-split (chI=bid&7=XCD) kept: xt channel slice (1.97MB) L2-resident.
__global__ __launch_bounds__(576)
void im2col_k4(const ushort* __restrict__ xt,
               const float* __restrict__ m_arr,
               const float* __restrict__ off_arr,
               ushort* __restrict__ colg) {
    __shared__ __align__(16) ushort tb[36 * TSTR_];   // 37440 B

    const int tid  = threadIdx.x;
    const int lane = tid & 63;
    const int wv   = tid >> 6;            // 0..8
    const int bid  = (int)blockIdx.x;
    const int chI  = bid & 7;             // chunk == XCD slot
    const int pbk  = bid >> 3;            // 0..479 pixel-block
    const int pb   = pbk * PT2_;
    const int b    = pb / HW_;
    const int hw0  = pb % HW_;
    const ushort* xtb = xt + (long)b * HW_ * CH_;
    ushort* cgo = colg + (long)pbk * (NCHK_ * COLW_) + (long)chI * COLW_;

    const int sseg = lane & 3;
    const int qd   = lane >> 2;
    const int cb0  = chI * CPC_ + sseg * 8;

    int   coff[4][4];
    float cwgt[4][4];
    int   ldst[4];
    #pragma unroll
    for (int g = 0; g < 4; ++g) {
        int pr = g * 144 + wv * 16 + qd;   // bijective over 0..575
        int px = pr & 63, kt = pr >> 6;
        int hw = hw0 + px;
        int pix = pb + px;
        int h  = hw / W_, w_ = hw % W_;
        float m    = m_arr[pix];
        float2 ohw = *(const float2*)(off_arr + (long)pix * 18 + 2 * kt);
        float py  = (float)(h  + (kt / 3 - 1)) + ohw.x;
        float pxf = (float)(w_ + (kt % 3 - 1)) + ohw.y;
        float y0f = floorf(py), x0f = floorf(pxf);
        float dy = py - y0f,   dx = pxf - x0f;
        int y0 = (int)y0f, x0i = (int)x0f;
        int y1 = y0 + 1,   x1  = x0i + 1;
        float vy0 = (y0  >= 0 && y0  < H_) ? 1.f : 0.f;
        float vy1 = (y1  >= 0 && y1  < H_) ? 1.f : 0.f;
        float vx0 = (x0i >= 0 && x0i < W_) ? 1.f : 0.f;
        float vx1 = (x1  >= 0 && x1  < W_) ? 1.f : 0.f;
        int cy0 = min(max(y0, 0),  H_-1), cy1 = min(max(y1, 0), H_-1);
        int cx0 = min(max(x0i, 0), W_-1), cx1 = min(max(x1, 0), W_-1);
        coff[g][0] = (cy0*W_ + cx0) * CH_ + cb0;  cwgt[g][0] = (1.f-dy)*(1.f-dx)*vy0*vx0*m;
        coff[g][1] = (cy0*W_ + cx1) * CH_ + cb0;  cwgt[g][1] = (1.f-dy)*dx      *vy0*vx1*m;
        coff[g][2] = (cy1*W_ + cx0) * CH_ + cb0;  cwgt[g][2] = dy      *(1.f-dx)*vy1*vx0*m;
        coff[g][3] = (cy1*W_ + cx1) * CH_ + cb0;  cwgt[g][3] = dy      *dx      *vy1*vx1*m;
        ldst[g] = (kt * 4 + sseg) * TSTR_ + px * 8;   // transpose-buffer slot
    }

    // phase 1: 16 coalesced gathers -> blend -> 4 LDS writes
    bf16x8 d[4][4];
    #pragma unroll
    for (int g = 0; g < 4; ++g)
        #pragma unroll
        for (int c = 0; c < 4; ++c)
            d[g][c] = *(const bf16x8*)(xtb + coff[g][c]);
    #pragma unroll
    for (int g = 0; g < 4; ++g) {
        float a8[8];
        #pragma unroll
        for (int j = 0; j < 8; ++j) a8[j] = 0.f;
        #pragma unroll
        for (int c = 0; c < 4; ++c) {
            float wgt = cwgt[g][c];
            #pragma unroll
            for (int j = 0; j < 8; ++j)
                a8[j] = fmaf(wgt, bf2f((ushort)d[g][c][j]), a8[j]);
        }
        bf16x8 o;
        #pragma unroll
        for (int j = 0; j < 8; ++j) o[j] = (short)f2bf(a8[j]);
        *(bf16x8*)(&tb[ldst[g]]) = o;
    }
    __syncthreads();

    // phase 2: granule-major re-read (linear b128) -> 1KB-contiguous stores
    #pragma unroll
    for (int g = 0; g < 4; ++g) {
        const int G = g * 9 + wv;          // 0..35
        bf16x8 o = *(const bf16x8*)(&tb[G * TSTR_ + lane * 8]);
        *(bf16x8*)(cgo + (G * 64 + lane) * 8) = o;
    }
}

// ======== v17b: PT=128 GEMM — deep per-chunk compute covers stage ========
// 240 blocks x 9 waves. LDS 147456B (dbuf x 2 halves x 18432B): 1 block/CU.
// Per chunk per SIMD: 2 waves x 144 MFMA x ~4.8cy ~ 1380 cyc > L3 latency,
// so the depth-1 prefetch (STAGE before COMPUTE, __syncthreads after) is
// fully covered — the drain lands on completed loads. Weights reused for
// 128 px per fetch (2x gemm4); next-ks weight frags prefetched to regs.
__global__ __launch_bounds__(576, 1)
void conv_gemm5(const float* __restrict__ x,
                const ushort* __restrict__ colg,
                const ushort* __restrict__ wp2,
                const float* __restrict__ bias,
                float* __restrict__ out) {
    __shared__ __align__(16) ushort colL[4 * COLW_];   // 147456 B

    const int tid  = threadIdx.x;
    const int lane = tid & 63;
    const int wv   = tid >> 6;            // 0..8
    const int l15  = lane & 15;
    const int l16  = lane >> 4;
    const int bid  = (int)blockIdx.x;     // 0..239 (identity; no straddle)
    const int pb   = bid * PT5_;
    const int b    = pb / HW_;
    const int hw0  = pb % HW_;
    const long xb  = (long)b * CH_ * HW_;
    const long pbk64 = (long)bid * 2;     // two 64px col blocks

    f32x4 acc[2][8];
    #pragma unroll
    for (int m = 0; m < 2; ++m)
        #pragma unroll
        for (int n = 0; n < 8; ++n)
            acc[m][n] = (f32x4)(0.f);

    const int rg0 = wv * 2;
    const int mg  = wv * 32;

    auto STAGE = [&](int chI, int bufi) {
        #pragma unroll
        for (int hf = 0; hf < 2; ++hf) {
            const ushort* src = colg + ((pbk64 + hf) * NCHK_ + chI) * COLW_;
            ushort* dst = colL + (bufi * 2 + hf) * COLW_;
            #pragma unroll
            for (int i = 0; i < 4; ++i) {
                const int go = (wv * 4 + i) * 512;
                gld_lds16(src + go + lane * 8, dst + go);
            }
        }
    };
    auto COMPUTE = [&](int bufi, int chI) {
        if (wv < 8) {
            const ushort* wbase = wp2 + (((long)rg0 * NKST_ + chI * K2_) << 9) + (lane << 3);
            const long rstep = (long)NKST_ << 9;
            bf16x8 a0 = *(const bf16x8*)(wbase);
            bf16x8 a1 = *(const bf16x8*)(wbase + rstep);
            #pragma unroll
            for (int ks = 0; ks < K2_; ++ks) {
                bf16x8 a0n, a1n;
                if (ks < K2_ - 1) {                     // prefetch next ks
                    a0n = *(const bf16x8*)(wbase + ((ks + 1) << 9));
                    a1n = *(const bf16x8*)(wbase + rstep + ((ks + 1) << 9));
                }
                const ushort* cb0 = &colL[(bufi * 2) * COLW_ + ((ks * 4 + l16) * 64 + l15) * 8];
                const ushort* cb1 = cb0 + COLW_;
                bf16x8 b0 = *(const bf16x8*)(cb0);
                bf16x8 b1 = *(const bf16x8*)(cb0 + 128);
                bf16x8 b2 = *(const bf16x8*)(cb0 + 256);
                bf16x8 b3 = *(const bf16x8*)(cb0 + 384);
                bf16x8 b4 = *(const bf16x8*)(cb1);
                bf16x8 b5 = *(const bf16x8*)(cb1 + 128);
                bf16x8 b6 = *(const bf16x8*)(cb1 + 256);
                bf16x8 b7 = *(const bf16x8*)(cb1 + 384);
                __builtin_amdgcn_s_setprio(1);
                acc[0][0] = __builtin_amdgcn_mfma_f32_16x16x32_bf16(a0, b0, acc[0][0], 0, 0, 0);
                acc[0][1] = __builtin_amdgcn_mfma_f32_16x16x32_bf16(a0, b1, acc[0][1], 0, 0, 0);
                acc[0][2] = __builtin_amdgcn_mfma_f32_16x16x32_bf16(a0, b2, acc[0][2], 0, 0, 0);
                acc[0][3] = __builtin_amdgcn_mfma_f32_16x16x32_bf16(a0, b3, acc[0][3], 0, 0, 0);
                acc[0][4] = __builtin_amdgcn_mfma_f32_16x16x32_bf16(a0, b4, acc[0][4], 0, 0, 0);
                acc[0][5] = __builtin_amdgcn_mfma_f32_16x16x32_bf16(a0, b5, acc[0][5], 0, 0, 0);
                acc[0][6] = __builtin_amdgcn_mfma_f32_16x16x32_bf16(a0, b6, acc[0][6], 0, 0, 0);
                acc[0][7] = __builtin_amdgcn_mfma_f32_16x16x32_bf16(a0, b7, acc[0][7], 0, 0, 0);
                acc[1][0] = __builtin_amdgcn_mfma_f32_16x16x32_bf16(a1, b0, acc[1][0], 0, 0, 0);
                acc[1][1] = __builtin_amdgcn_mfma_f32_16x16x32_bf16(a1, b1, acc[1][1], 0, 0, 0);
                acc[1][2] = __builtin_amdgcn_mfma_f32_16x16x32_bf16(a1, b2, acc[1][2], 0, 0, 0);
                acc[1][3] = __builtin_amdgcn_mfma_f32_16x16x32_bf16(a1, b3, acc[1][3], 0, 0, 0);
                acc[1][4] = __builtin_amdgcn_mfma_f32_16x16x32_bf16(a1, b4, acc[1][4], 0, 0, 0);
                acc[1][5] = __builtin_amdgcn_mfma_f32_16x16x32_bf16(a1, b5, acc[1][5], 0, 0, 0);
                acc[1][6] = __builtin_amdgcn_mfma_f32_16x16x32_bf16(a1, b6, acc[1][6], 0, 0, 0);
                acc[1][7] = __builtin_amdgcn_mfma_f32_16x16x32_bf16(a1, b7, acc[1][7], 0, 0, 0);
                __builtin_amdgcn_s_setprio(0);
                if (ks < K2_ - 1) { a0 = a0n; a1 = a1n; }
            }
        }
    };

    STAGE(0, 0);
    __syncthreads();                       // buf0 ready
    for (int chI = 0; chI < NCHK_; ++chI) {
        const int cur = chI & 1, nxt = cur ^ 1;
        if (chI < NCHK_ - 1) STAGE(chI + 1, nxt);   // covered by 1380cy compute
        COMPUTE(cur, chI);
        __syncthreads();
    }

    if (wv < 8) {
        #pragma unroll
        for (int m = 0; m < 2; ++m)
            #pragma unroll
            for (int n = 0; n < 8; ++n)
                #pragma unroll
                for (int r = 0; r < 4; ++r) {
                    int o  = mg + m * 16 + l16 * 4 + r;
                    int hw = hw0 + n * 16 + l15;
                    long oi = xb + (long)o * HW_ + hw;
                    out[oi] = acc[m][n][r] + bias[o] + x[oi];
                }
    }
}

// ======== v11 (proven 140 us) — mid-tier if ws can't hold col ========
__global__ __launch_bounds__(576)
void conv_mfma11(const float* __restrict__ x,
                 const ushort* __restrict__ xt,
                 const ushort* __restrict__ wp2,
                 const float* __restrict__ prob,
                 const float* __restrict__ table,
                 const float* __restrict__ bias,
                 float* __restrict__ out) {
    __shared__ __align__(16) ushort col[2][PT2_ * LSTR_];   // 75776 B
    __shared__ float off_l[PT2_ * 18];
    __shared__ float m_l[PT2_];

    const int tid  = threadIdx.x;
    const int lane = tid & 63;
    const int wv   = tid >> 6;
    const int l15  = lane & 15;
    const int l16  = lane >> 4;
    const int bid  = (int)blockIdx.x;
    const int bswz = (bid & 7) * (NBLK_ / 8) + (bid >> 3);
    const int pb   = bswz * PT2_;
    const int b    = pb / HW_;
    const int hw0  = pb % HW_;
    const long xb  = (long)b * CH_ * HW_;
    const ushort* xtb = xt + (long)b * HW_ * CH_;

    if (tid < PT2_) {
        const int px = tid;
        const int hw = hw0 + px;
        const float* pr = prob + (long)b * A_ * HW_ + hw;
        float v0 = -1e30f, v1 = -1e30f, v2 = -1e30f;
        int   i0 = 0, i1 = 0, i2 = 0;
        #pragma unroll 4
        for (int a = 0; a < A_; ++a) {
            float v = pr[(long)a * HW_];
            if (v > v0)      { v2=v1; i2=i1; v1=v0; i1=i0; v0=v; i0=a; }
            else if (v > v1) { v2=v1; i2=i1; v1=v;  i1=a; }
            else if (v > v2) { v2=v;  i2=a; }
        }
        float e1 = expf(v1 - v0), e2 = expf(v2 - v0);
        float inv = 1.0f / (1.0f + e1 + e2);
        float s0 = inv, s1 = e1*inv, s2 = e2*inv;
        float hard = (v0 > 0.5f) ? 1.0f : 0.0f;
        m_l[px] = v0;
        const float* t0 = table + ((long)i0 * 18) * HW_ + hw;
        const float* t1 = table + ((long)i1 * 18) * HW_ + hw;
        const float* t2 = table + ((long)i2 * 18) * HW_ + hw;
        #pragma unroll
        for (int c = 0; c < 18; ++c) {
            float o = s0 * t0[(long)c * HW_] + s1 * t1[(long)c * HW_] + s2 * t2[(long)c * HW_];
            off_l[px * 18 + c] = o * hard;
        }
    }
    __syncthreads();

    const int sseg = lane & 3;
    const int qd   = lane >> 2;
    int   coff[4][4];
    float cwgt[4][4];
    int   dsto[4];
    #pragma unroll
    for (int g = 0; g < 4; ++g) {
        int pr = g * 144 + wv * 16 + qd;
        int px = pr & 63, kt = pr >> 6;
        int hw = hw0 + px;
        int h  = hw / W_, w_ = hw % W_;
        float m    = m_l[px];
        float offh = off_l[px * 18 + 2*kt];
        float offw = off_l[px * 18 + 2*kt + 1];
        float py  = (float)(h  + (kt / 3 - 1)) + offh;
        float pxf = (float)(w_ + (kt % 3 - 1)) + offw;
        float y0f = floorf(py), x0f = floorf(pxf);
        float dy = py - y0f,   dx = pxf - x0f;
        int y0 = (int)y0f, x0i = (int)x0f;
        int y1 = y0 + 1,   x1  = x0i + 1;
        float vy0 = (y0  >= 0 && y0  < H_) ? 1.f : 0.f;
        float vy1 = (y1  >= 0 && y1  < H_) ? 1.f : 0.f;
        float vx0 = (x0i >= 0 && x0i < W_) ? 1.f : 0.f;
        float vx1 = (x1  >= 0 && x1  < W_) ? 1.f : 0.f;
        int cy0 = min(max(y0, 0),  H_-1), cy1 = min(max(y1, 0), H_-1);
        int cx0 = min(max(x0i, 0), W_-1), cx1 = min(max(x1, 0), W_-1);
        coff[g][0] = (cy0*W_ + cx0) * CH_;  cwgt[g][0] = (1.f-dy)*(1.f-dx)*vy0*vx0*m;
        coff[g][1] = (cy0*W_ + cx1) * CH_;  cwgt[g][1] = (1.f-dy)*dx      *vy0*vx1*m;
        coff[g][2] = (cy1*W_ + cx0) * CH_;  cwgt[g][2] = dy      *(1.f-dx)*vy1*vx0*m;
        coff[g][3] = (cy1*W_ + cx1) * CH_;  cwgt[g][3] = dy      *dx      *vy1*vx1*m;
        dsto[g] = px * LSTR_ + kt * CPC_ + sseg * 8;
    }

    f32x4 acc[2][4];
    #pragma unroll
    for (int m = 0; m < 2; ++m)
        #pragma unroll
        for (int n = 0; n < 4; ++n)
            acc[m][n] = (f32x4)(0.f);

    const int rg0 = wv * 2;
    const int mg  = wv * 32;

    bf16x8 d[2][4];

    auto LOADpair = [&](int chI, int g0) {
        const int cb0 = chI * CPC_ + sseg * 8;
        #pragma unroll
        for (int gg = 0; gg < 2; ++gg)
            #pragma unroll
            for (int c = 0; c < 4; ++c)
                d[gg][c] = *(const bf16x8*)(xtb + coff[g0 + gg][c] + cb0);
    };
    auto WRITEpair = [&](int bufi, int g0) {
        #pragma unroll
        for (int gg = 0; gg < 2; ++gg) {
            float a8[8];
            #pragma unroll
            for (int j = 0; j < 8; ++j) a8[j] = 0.f;
            #pragma unroll
            for (int c = 0; c < 4; ++c) {
                float wgt = cwgt[g0 + gg][c];
                #pragma unroll
                for (int j = 0; j < 8; ++j)
                    a8[j] = fmaf(wgt, bf2f((ushort)d[gg][c][j]), a8[j]);
            }
            bf16x8 o;
            #pragma unroll
            for (int j = 0; j < 8; ++j) o[j] = (short)f2bf(a8[j]);
            *(bf16x8*)(&col[bufi][dsto[g0 + gg]]) = o;
        }
    };
    auto COMPUTEhalf = [&](int bufi, int chI, int ks0, int ks1) {
        if (wv < 8) {
            for (int ks = ks0; ks < ks1; ++ks) {
                const int kst = chI * K2_ + ks;
                const ushort* wr = wp2 + (((long)rg0 * NKST_ + kst) << 9) + (lane << 3);
                bf16x8 a0 = *(const bf16x8*)(wr);
                bf16x8 a1 = *(const bf16x8*)(wr + (1l * NKST_ << 9));
                const ushort* cb = &col[bufi][l15 * LSTR_ + ks * 32 + 8 * l16];
                bf16x8 b0 = *(const bf16x8*)(cb);
                bf16x8 b1 = *(const bf16x8*)(cb + 16 * LSTR_);
                bf16x8 b2 = *(const bf16x8*)(cb + 32 * LSTR_);
                bf16x8 b3 = *(const bf16x8*)(cb + 48 * LSTR_);
                __builtin_amdgcn_s_setprio(1);
                acc[0][0] = __builtin_amdgcn_mfma_f32_16x16x32_bf16(a0, b0, acc[0][0], 0, 0, 0);
                acc[0][1] = __builtin_amdgcn_mfma_f32_16x16x32_bf16(a0, b1, acc[0][1], 0, 0, 0);
                acc[0][2] = __builtin_amdgcn_mfma_f32_16x16x32_bf16(a0, b2, acc[0][2], 0, 0, 0);
                acc[0][3] = __builtin_amdgcn_mfma_f32_16x16x32_bf16(a0, b3, acc[0][3], 0, 0, 0);
                acc[1][0] = __builtin_amdgcn_mfma_f32_16x16x32_bf16(a1, b0, acc[1][0], 0, 0, 0);
                acc[1][1] = __builtin_amdgcn_mfma_f32_16x16x32_bf16(a1, b1, acc[1][1], 0, 0, 0);
                acc[1][2] = __builtin_amdgcn_mfma_f32_16x16x32_bf16(a1, b2, acc[1][2], 0, 0, 0);
                acc[1][3] = __builtin_amdgcn_mfma_f32_16x16x32_bf16(a1, b3, acc[1][3], 0, 0, 0);
                __builtin_amdgcn_s_setprio(0);
            }
        }
    };

    LOADpair(0, 0); WRITEpair(0, 0);
    LOADpair(0, 2); WRITEpair(0, 2);
    __syncthreads();

    for (int chI = 0; chI < NCHK_; ++chI) {
        const int cur = chI & 1, nxt = cur ^ 1;
        const bool pf = (chI < NCHK_ - 1);
        if (pf) LOADpair(chI + 1, 0);
        COMPUTEhalf(cur, chI, 0, 4);
        if (pf) { WRITEpair(nxt, 0); LOADpair(chI + 1, 2); }
        COMPUTEhalf(cur, chI, 4, 9);
        if (pf) WRITEpair(nxt, 2);
        __syncthreads();
    }

    if (wv < 8) {
        #pragma unroll
        for (int m = 0; m < 2; ++m)
            #pragma unroll
            for (int n = 0; n < 4; ++n)
                #pragma unroll
                for (int r = 0; r < 4; ++r) {
                    int o  = mg + m * 16 + l16 * 4 + r;
                    int hw = hw0 + n * 16 + l15;
                    long oi = xb + (long)o * HW_ + hw;
                    out[oi] = acc[m][n][r] + bias[o] + x[oi];
                }
    }
}

// ======== v2 fallback (used if ws too small) ========
__global__ __launch_bounds__(576)
void conv_mfma2(const float* __restrict__ x,
                const ushort* __restrict__ wp,
                const float* __restrict__ bias,
                const float* __restrict__ m_arr,
                const float* __restrict__ off_arr,
                float* __restrict__ out) {
    __shared__ __align__(16) ushort col[PT2_ * LSTR_];

    const int tid  = threadIdx.x;
    const int lane = tid & 63;
    const int wv   = tid >> 6;
    const int l15  = lane & 15;
    const int l16  = lane >> 4;
    const int pb   = blockIdx.x * PT2_;
    const int b    = pb / HW_;
    const int hw0  = pb % HW_;
    const long xb  = (long)b * CH_ * HW_;

    int   id0, id1, id2, id3;
    float wg0, wg1, wg2, wg3;
    {
        int px = lane, kt = wv;
        int hw = hw0 + px;
        int h  = hw / W_, w_ = hw % W_;
        int pix = b * HW_ + hw;
        float m    = m_arr[pix];
        float offh = off_arr[(long)pix * 18 + 2*kt];
        float offw = off_arr[(long)pix * 18 + 2*kt + 1];
        float py = (float)(h  + (kt / 3 - 1)) + offh;
        float px_= (float)(w_ + (kt % 3 - 1)) + offw;
        float y0f = floorf(py), x0f = floorf(px_);
        float dy = py - y0f,   dx = px_ - x0f;
        int y0 = (int)y0f, x0 = (int)x0f;
        int y1 = y0 + 1,   x1 = x0 + 1;
        float vy0 = (y0 >= 0 && y0 < H_) ? 1.f : 0.f;
        float vy1 = (y1 >= 0 && y1 < H_) ? 1.f : 0.f;
        float vx0 = (x0 >= 0 && x0 < W_) ? 1.f : 0.f;
        float vx1 = (x1 >= 0 && x1 < W_) ? 1.f : 0.f;
        int cy0 = min(max(y0, 0), H_-1), cy1 = min(max(y1, 0), H_-1);
        int cx0 = min(max(x0, 0), W_-1), cx1 = min(max(x1, 0), W_-1);
        id0 = cy0*W_ + cx0;  wg0 = (1.f-dy)*(1.f-dx)*vy0*vx0*m;
        id1 = cy0*W_ + cx1;  wg1 = (1.f-dy)*dx      *vy0*vx1*m;
        id2 = cy1*W_ + cx0;  wg2 = dy      *(1.f-dx)*vy1*vx0*m;
        id3 = cy1*W_ + cx1;  wg3 = dy      *dx      *vy1*vx1*m;
    }

    f32x4 acc[4][2];
    #pragma unroll
    for (int m = 0; m < 4; ++m)
        #pragma unroll
        for (int n = 0; n < 2; ++n)
            acc[m][n] = (f32x4)(0.f);

    const int mg = (wv & 3) * 64;
    const int pg = (wv >> 2) * 32;

    for (int chI = 0; chI < NCHK_; ++chI) {
        __syncthreads();
        {
            const int c0 = chI * CPC_;
            ushort* dst = &col[lane * LSTR_ + wv * CPC_];
            #pragma unroll
            for (int c8 = 0; c8 < 4; ++c8) {
                bf16x8 pk;
                #pragma unroll
                for (int j = 0; j < 8; ++j) {
                    const float* xs = x + xb + (long)(c0 + c8*8 + j) * HW_;
                    float v = wg0 * xs[id0] + wg1 * xs[id1]
                            + wg2 * xs[id2] + wg3 * xs[id3];
                    pk[j] = (short)f2bf(v);
                }
                *(bf16x8*)(dst + c8 * 8) = pk;
            }
        }
        __syncthreads();
        if (wv < 8) {
            #pragma unroll
            for (int ks = 0; ks < K2_; ++ks) {
                const int kg = chI * KC_ + ks * 32 + 8 * l16;
                const ushort* wr = wp + (long)(mg + l15) * KTOT_ + kg;
                bf16x8 a0 = *(const bf16x8*)(wr);
                bf16x8 a1 = *(const bf16x8*)(wr + 16 * KTOT_);
                bf16x8 a2 = *(const bf16x8*)(wr + 32 * KTOT_);
                bf16x8 a3 = *(const bf16x8*)(wr + 48 * KTOT_);
                const ushort* cb = &col[(pg + l15) * LSTR_ + ks * 32 + 8 * l16];
                bf16x8 b0 = *(const bf16x8*)(cb);
                bf16x8 b1 = *(const bf16x8*)(cb + 16 * LSTR_);
                acc[0][0] = __builtin_amdgcn_mfma_f32_16x16x32_bf16(a0, b0, acc[0][0], 0, 0, 0);
                acc[0][1] = __builtin_amdgcn_mfma_f32_16x16x32_bf16(a0, b1, acc[0][1], 0, 0, 0);
                acc[1][0] = __builtin_amdgcn_mfma_f32_16x16x32_bf16(a1, b0, acc[1][0], 0, 0, 0);
                acc[1][1] = __builtin_amdgcn_mfma_f32_16x16x32_bf16(a1, b1, acc[1][1], 0, 0, 0);
                acc[2][0] = __builtin_amdgcn_mfma_f32_16x16x32_bf16(a2, b0, acc[2][0], 0, 0, 0);
                acc[2][1] = __builtin_amdgcn_mfma_f32_16x16x32_bf16(a2, b1, acc[2][1], 0, 0, 0);
                acc[3][0] = __builtin_amdgcn_mfma_f32_16x16x32_bf16(a3, b0, acc[3][0], 0, 0, 0);
                acc[3][1] = __builtin_amdgcn_mfma_f32_16x16x32_bf16(a3, b1, acc[3][1], 0, 0, 0);
            }
        }
    }

    if (wv < 8) {
        #pragma unroll
        for (int m = 0; m < 4; ++m)
            #pragma unroll
            for (int n = 0; n < 2; ++n)
                #pragma unroll
                for (int r = 0; r < 4; ++r) {
                    int o  = mg + m * 16 + l16 * 4 + r;
                    int hw = hw0 + pg + n * 16 + l15;
                    long oi = xb + (long)o * HW_ + hw;
                    out[oi] = acc[m][n][r] + bias[o] + x[oi];
                }
    }
}

extern "C" void kernel_launch(void* const* d_in, const int* in_sizes, int n_in,
                              void* d_out, int out_size, void* d_ws, size_t ws_size,
                              hipStream_t stream) {
    const float* x      = (const float*)d_in[0];
    const float* prob   = (const float*)d_in[1];
    const float* table  = (const float*)d_in[2];
    const float* weight = (const float*)d_in[3];
    const float* bias   = (const float*)d_in[4];
    float* out = (float*)d_out;

    const size_t wp_bytes  = (size_t)CH_ * KTOT_ * 2;          // 1,179,648
    const size_t m_bytes   = (size_t)NPIX_ * 4;                // 122,880
    const size_t off_bytes = (size_t)NPIX_ * 18 * 4;           // 2,211,840
    const size_t xt_bytes  = (size_t)NPIX_ * CH_ * 2;          // 15,728,640
    const size_t col_bytes = (size_t)NBLK_ * NCHK_ * COLB_;    // 141,557,760

    ushort* wp_ws  = (ushort*)d_ws;
    float*  m_ws   = (float*)((char*)d_ws + wp_bytes);
    float*  off_ws = (float*)((char*)d_ws + wp_bytes + m_bytes);
    ushort* xt_ws  = (ushort*)((char*)d_ws + wp_bytes + m_bytes + off_bytes);
    ushort* col_ws = (ushort*)((char*)d_ws + wp_bytes + m_bytes + off_bytes + xt_bytes);

    const size_t need_v11 = wp_bytes + m_bytes + off_bytes + xt_bytes;
    const size_t need_v17 = need_v11 + col_bytes;

    if (ws_size >= need_v17) {
        prep_weight2<<<(CH_ * KTOT_ + 255) / 256, 256, 0, stream>>>(weight, wp_ws);
        prep_xt<<<(HW_ / 128) * 4 * B_, 256, 0, stream>>>(x, xt_ws);
        gating_kernel<<<NPIX_ / 256, 256, 0, stream>>>(prob, table, m_ws, off_ws);
        im2col_k4<<<NBLK_ * NCHK_, 576, 0, stream>>>(xt_ws, m_ws, off_ws, col_ws);
        conv_gemm5<<<NB5_, 576, 0, stream>>>(x, col_ws, wp_ws, bias, out);
    } else if (ws_size >= need_v11) {
        prep_weight2<<<(CH_ * KTOT_ + 255) / 256, 256, 0, stream>>>(weight, wp_ws);
        prep_xt<<<(HW_ / 128) * 4 * B_, 256, 0, stream>>>(x, xt_ws);
        conv_mfma11<<<NBLK_, 576, 0, stream>>>(x, xt_ws, wp_ws, prob, table, bias, out);
    } else {
        gating_kernel<<<NPIX_ / 256, 256, 0, stream>>>(prob, table, m_ws, off_ws);
        prep_weight<<<(CH_ * KTOT_ + 255) / 256, 256, 0, stream>>>(weight, wp_ws);
        conv_mfma2<<<NPIX_ / PT2_, 576, 0, stream>>>(x, wp_ws, bias, m_ws, off_ws, out);
    }
}